// Round 3
// baseline (18602.377 us; speedup 1.0000x reference)
//
#include <hip/hip_runtime.h>
#include <hip/hip_bf16.h>

// Bidirectional GRU encoder, B=64 T=1024 D=300 U=300.
// Round 7: stall elimination on the R6 batch-split scan (4 WG/dir x 16 rows).
// - Parity double-buffered h in LDS -> ONE raw s_barrier per step with
//   lgkmcnt-only drain (no vmcnt(0) store/load drain per step).
// - xp gate loads hoisted to step top (HBM latency hidden under MFMA phase).
// - Epilogue needs no preceding barrier (register-only inputs, writes par^1).
// - launch_bounds(512,2) pins the 256-reg/wave budget; fast exp-based
//   tanh/sigmoid; s_setprio(1) around the MFMA region.

#define B_   64
#define T_   1024
#define D_   300
#define U_   300
#define NU   900      // 3U
#define KP   320      // padded K for input GEMM
#define NP   960      // padded N width of k_pad
#define XPW  912      // xp row stride (elements)
#define KB_  10       // K blocks of 32 (320/32)
#define KRES 2        // K blocks LDS-resident in scan
#define HSP  328      // h LDS row stride (shorts): 656B -> 2-way-free bank stride
#define FRAGS_PER_DIR 570   // 3 waves*90 + 5 waves*60
#define NRESF 114           // resident frags per dir (3*18 + 5*12)
#define NWGM 4              // m-groups (16 rows each)

typedef short short8 __attribute__((ext_vector_type(8)));
typedef float floatx4 __attribute__((ext_vector_type(4)));

__device__ __forceinline__ float b2f_bits(unsigned short u) {
  union { unsigned int i; float f; } v; v.i = ((unsigned int)u) << 16; return v.f;
}
__device__ __forceinline__ unsigned short f2b(float f) {
  __hip_bfloat16 h = __float2bfloat16(f);  // RNE
  return *reinterpret_cast<unsigned short*>(&h);
}
__device__ __forceinline__ float sigm_f(float x) {
  float e = __expf(-x);
  return __fdividef(1.f, 1.f + e);
}
__device__ __forceinline__ float tanh_f(float x) {
  float e = __expf(2.f * x);           // inf for large x -> 1-0 = 1; 0 for very neg -> -1
  return 1.f - __fdividef(2.f, e + 1.f);
}

// ---------------- K_detect: input dtype + mask dtype flags ----------------
__global__ __launch_bounds__(64) void k_detect(const unsigned int* __restrict__ xw,
                                               const unsigned char* __restrict__ mb,
                                               int* __restrict__ flags) {
  __shared__ int red[64];
  int tid = threadIdx.x;
  int hits = 0;
  for (int i = tid; i < 2048; i += 64) {
    unsigned int lo = xw[i] & 0xFFFFu;
    int e = (int)((lo >> 7) & 0xFF);
    if (e >= 105 && e <= 135) hits++;   // plausible bf16 exponent for N(0,1)
  }
  red[tid] = hits;
  __syncthreads();
  if (tid == 0) {
    int s = 0;
    for (int i = 0; i < 64; ++i) s += red[i];
    flags[0] = (s >= 1024) ? 1 : 0;
    unsigned char b0 = mb[0], b1 = mb[1];
    flags[1] = (b1 == 0) ? 0 : ((b0 == 1 && b1 == 1) ? 1 : 2);
  }
}

// ---------------- K0: lengths from mask ----------------
__global__ __launch_bounds__(256) void k_lengths(const unsigned char* __restrict__ mraw,
                                                 const int* __restrict__ flags,
                                                 int* __restrict__ lens) {
  __shared__ int red[256];
  int b = blockIdx.x, tid = threadIdx.x;
  int mt = flags[1];
  int s = 0;
  if (mt == 0) {
    const int* m = (const int*)mraw;
    for (int t = tid; t < T_; t += 256) s += m[(size_t)b * T_ + t] ? 1 : 0;
  } else if (mt == 1) {
    for (int t = tid; t < T_; t += 256) s += mraw[(size_t)b * T_ + t] ? 1 : 0;
  } else {
    const unsigned short* m = (const unsigned short*)mraw;
    for (int t = tid; t < T_; t += 256) s += m[(size_t)b * T_ + t] ? 1 : 0;
  }
  red[tid] = s; __syncthreads();
  for (int off = 128; off > 0; off >>= 1) {
    if (tid < off) red[tid] += red[tid + off];
    __syncthreads();
  }
  if (tid == 0) lens[b] = red[0];
}

// ---------------- K1: pad x -> [65536,320] bf16 ----------------
__global__ __launch_bounds__(256) void k_xpad(const void* __restrict__ xraw,
                                              const int* __restrict__ flags,
                                              unsigned short* __restrict__ xp) {
  int id = blockIdx.x * 256 + threadIdx.x;
  int row = id / 40, seg = id % 40;
  int kbase = seg * 8;
  int bf = flags[0];
  unsigned short v[8];
  if (bf) {
    const unsigned short* x = (const unsigned short*)xraw;
#pragma unroll
    for (int i = 0; i < 8; ++i) {
      int k = kbase + i;
      v[i] = (k < D_) ? x[(size_t)row * D_ + k] : (unsigned short)0;
    }
  } else {
    const float* x = (const float*)xraw;
#pragma unroll
    for (int i = 0; i < 8; ++i) {
      int k = kbase + i;
      v[i] = (k < D_) ? f2b(x[(size_t)row * D_ + k]) : (unsigned short)0;
    }
  }
  uint4 o;
  o.x = (unsigned)v[0] | ((unsigned)v[1] << 16);
  o.y = (unsigned)v[2] | ((unsigned)v[3] << 16);
  o.z = (unsigned)v[4] | ((unsigned)v[5] << 16);
  o.w = (unsigned)v[6] | ((unsigned)v[7] << 16);
  *(uint4*)(xp + (size_t)row * KP + kbase) = o;
}

// ---------------- K2: pad k_{fwd,bwd} -> [2][320,960] bf16 ----------------
__global__ __launch_bounds__(256) void k_wpad(const void* __restrict__ kf,
                                              const void* __restrict__ kb,
                                              const int* __restrict__ flags,
                                              unsigned short* __restrict__ kp) {
  int id = blockIdx.x * 256 + threadIdx.x;
  if (id >= 2 * KP * NP) return;
  int dir = id / (KP * NP);
  int r = id % (KP * NP);
  int k = r / NP, n = r % NP;
  int bf = flags[0];
  unsigned short v = 0;
  if (k < D_ && n < NU) {
    size_t si = (size_t)k * NU + n;
    if (bf) v = ((const unsigned short*)(dir ? kb : kf))[si];
    else    v = f2b(((const float*)(dir ? kb : kf))[si]);
  }
  kp[id] = v;
}

// ---------------- K_prep: canonical rk (bf16), biases (f32), wfc, bfc ----------------
__global__ __launch_bounds__(256) void k_prep(const void* __restrict__ rkf,
                                              const void* __restrict__ rkb,
                                              const void* __restrict__ bfw,
                                              const void* __restrict__ bbw,
                                              const void* __restrict__ wfc,
                                              const void* __restrict__ bfc,
                                              const int* __restrict__ flags,
                                              unsigned short* __restrict__ rkc,   // [2][300][900]
                                              float* __restrict__ biasc,          // [2][2][900]
                                              unsigned short* __restrict__ wfcc,  // [600][300]
                                              float* __restrict__ bfcc) {         // [300]
  int i = blockIdx.x * 256 + threadIdx.x;
  int bf = flags[0];
  if (i < 2 * D_ * NU) {
    int dir = i / (D_ * NU), r = i % (D_ * NU);
    const void* src = dir ? rkb : rkf;
    rkc[i] = bf ? ((const unsigned short*)src)[r] : f2b(((const float*)src)[r]);
  }
  if (i < 2 * 2 * NU) {
    int dir = i / (2 * NU), r = i % (2 * NU);
    const void* src = dir ? bbw : bfw;
    biasc[i] = bf ? b2f_bits(((const unsigned short*)src)[r]) : ((const float*)src)[r];
  }
  if (i < 2 * U_ * U_) {
    wfcc[i] = bf ? ((const unsigned short*)wfc)[i] : f2b(((const float*)wfc)[i]);
  }
  if (i < U_) {
    bfcc[i] = bf ? b2f_bits(((const unsigned short*)bfc)[i]) : ((const float*)bfc)[i];
  }
}

// ---------------- K_bpack: rk -> per-wave MFMA B-fragment stream ----------------
// Waves 0-2 own 3 u-blocks (ub0 = 3w), waves 3-7 own 2 (ub0 = 9+2(w-3)).
// n-tile nt = lb*3 + g. frag f = FB(w) + kb*NTC + nt.
__global__ __launch_bounds__(256) void k_bpack(const unsigned short* __restrict__ rkc,
                                               unsigned short* __restrict__ bpack) {
  int idx = blockIdx.x * 256 + threadIdx.x;
  const int total = 2 * FRAGS_PER_DIR * 512;
  if (idx >= total) return;
  int rem = idx;
  int j = rem & 7; rem >>= 3;
  int lane = rem & 63; rem >>= 6;
  int f = rem % FRAGS_PER_DIR;
  int dir = rem / FRAGS_PER_DIR;
  int w, fr, ntc;
  if (f < 270) { w = f / 90; fr = f - w * 90; ntc = 9; }
  else { int f2 = f - 270; w = 3 + f2 / 60; fr = f2 % 60; ntc = 6; }
  int kb = fr / ntc, nt = fr % ntc;
  int lb = nt / 3, g = nt % 3;
  int ub0 = (w < 3) ? w * 3 : 9 + (w - 3) * 2;
  int l15 = lane & 15, quad = lane >> 4;
  int k = kb * 32 + quad * 8 + j;
  int u = (ub0 + lb) * 16 + l15;
  unsigned short v = 0;
  if (k < U_ && u < U_) {
    v = rkc[(size_t)dir * U_ * NU + (size_t)k * NU + (size_t)g * U_ + u];
  }
  bpack[idx] = v;
}

// ---------------- K3: xp = x @ k + b_in, MFMA 16x16x32 bf16 ----------------
template <bool XPF32>
__global__ __launch_bounds__(256) void k_gemm(const unsigned short* __restrict__ xpad,
                                              const unsigned short* __restrict__ kpad,
                                              const float* __restrict__ biasc,
                                              void* __restrict__ xp_out) {
  __shared__ __align__(16) unsigned short As[64 * 40];
  __shared__ __align__(16) unsigned short Bs[64 * 40];  // transposed: [n][k]
  int tid = threadIdx.x;
  int wave = tid >> 6, lane = tid & 63;
  int m0 = blockIdx.x * 64, n0 = blockIdx.y * 64;
  int dir = blockIdx.z;
  const unsigned short* Bsrc = kpad + (size_t)dir * KP * NP;
  const float* bin = biasc + (size_t)dir * 2 * NU;

  floatx4 acc[4];
#pragma unroll
  for (int i = 0; i < 4; ++i) acc[i] = {0.f, 0.f, 0.f, 0.f};

  int arow = tid >> 2, aseg = tid & 3;
  int bk = tid & 31, bn8 = (tid >> 5) * 8;
  int fr = lane & 15, fq = lane >> 4;

  for (int kc = 0; kc < KP; kc += 32) {
    uint4 av = *(const uint4*)(xpad + (size_t)(m0 + arow) * KP + kc + aseg * 8);
    uint4 bv = *(const uint4*)(Bsrc + (size_t)(kc + bk) * NP + n0 + bn8);
    *(uint4*)(As + arow * 40 + aseg * 8) = av;
    unsigned short tmp[8];
    tmp[0] = bv.x & 0xffff; tmp[1] = bv.x >> 16;
    tmp[2] = bv.y & 0xffff; tmp[3] = bv.y >> 16;
    tmp[4] = bv.z & 0xffff; tmp[5] = bv.z >> 16;
    tmp[6] = bv.w & 0xffff; tmp[7] = bv.w >> 16;
#pragma unroll
    for (int i = 0; i < 8; ++i) Bs[(bn8 + i) * 40 + bk] = tmp[i];
    __syncthreads();
    short8 a = *(const short8*)(As + (wave * 16 + fr) * 40 + fq * 8);
#pragma unroll
    for (int nt = 0; nt < 4; ++nt) {
      short8 bfrag = *(const short8*)(Bs + (nt * 16 + fr) * 40 + fq * 8);
      acc[nt] = __builtin_amdgcn_mfma_f32_16x16x32_bf16(a, bfrag, acc[nt], 0, 0, 0);
    }
    __syncthreads();
  }
#pragma unroll
  for (int nt = 0; nt < 4; ++nt) {
    int col = n0 + nt * 16 + fr;
    if (col >= XPW) continue;
    float bi = (col < NU) ? bin[col] : 0.f;
#pragma unroll
    for (int r = 0; r < 4; ++r) {
      int m = m0 + wave * 16 + fq * 4 + r;
      float v = acc[nt][r] + bi;
      size_t idx = ((size_t)dir * 65536 + m) * XPW + col;
      if (XPF32) ((float*)xp_out)[idx] = v;
      else ((unsigned short*)xp_out)[idx] = f2b(v);
    }
  }
}

// ---------------- K4 helper: stream issue + xp loads + MFMA for one wave ----------------
template <int NTC, bool XPF32>
__device__ __forceinline__ void phase(floatx4 (&acc)[9], float (&X)[3][3][4],
                                      const unsigned short* __restrict__ bp,
                                      const unsigned short* __restrict__ sBw,
                                      const unsigned short (*hH)[HSP],
                                      const unsigned short (*hL)[HSP],
                                      const void* __restrict__ xp_all,
                                      const size_t* __restrict__ xbase,  // [4] per-r row base
                                      int t, const int (*xcol)[3],       // [lb][g]
                                      int l15, int quad) {
  short8 bA[NTC], bB[NTC];
  // issue stream loads for kb=KRES, KRES+1 first
#pragma unroll
  for (int nt = 0; nt < NTC; ++nt)
    bA[nt] = *(const short8*)(bp + ((size_t)(KRES * NTC + nt)) * 512);
#pragma unroll
  for (int nt = 0; nt < NTC; ++nt)
    bB[nt] = *(const short8*)(bp + ((size_t)((KRES + 1) * NTC + nt)) * 512);
  // xp loads for this step (consumed in epilogue, ~whole phase to hide latency)
#pragma unroll
  for (int r = 0; r < 4; ++r) {
    size_t ro = xbase[r] + (size_t)t * XPW;
    if (XPF32) {
      const float* xr = (const float*)xp_all + ro;
#pragma unroll
      for (int lb = 0; lb < 3; ++lb) {
        X[lb][0][r] = xr[xcol[lb][0]];
        X[lb][1][r] = xr[xcol[lb][1]];
        X[lb][2][r] = xr[xcol[lb][2]];
      }
    } else {
      const unsigned short* xr = (const unsigned short*)xp_all + ro;
#pragma unroll
      for (int lb = 0; lb < 3; ++lb) {
        X[lb][0][r] = b2f_bits(xr[xcol[lb][0]]);
        X[lb][1][r] = b2f_bits(xr[xcol[lb][1]]);
        X[lb][2][r] = b2f_bits(xr[xcol[lb][2]]);
      }
    }
  }
  __builtin_amdgcn_s_setprio(1);
  // LDS-resident kb = 0..KRES-1
#pragma unroll
  for (int kb = 0; kb < KRES; ++kb) {
    short8 ah = *(const short8*)&hH[l15][kb * 32 + quad * 8];
    short8 al = *(const short8*)&hL[l15][kb * 32 + quad * 8];
#pragma unroll
    for (int nt = 0; nt < NTC; ++nt) {
      short8 b = *(const short8*)(sBw + ((size_t)(kb * NTC + nt)) * 512);
      acc[nt] = __builtin_amdgcn_mfma_f32_16x16x32_bf16(ah, b, acc[nt], 0, 0, 0);
      acc[nt] = __builtin_amdgcn_mfma_f32_16x16x32_bf16(al, b, acc[nt], 0, 0, 0);
    }
  }
  // streamed kb = KRES..KB_-1, double-buffered
#pragma unroll
  for (int kb = KRES; kb < KB_; kb += 2) {
    {
      short8 ah = *(const short8*)&hH[l15][kb * 32 + quad * 8];
      short8 al = *(const short8*)&hL[l15][kb * 32 + quad * 8];
#pragma unroll
      for (int nt = 0; nt < NTC; ++nt) {
        acc[nt] = __builtin_amdgcn_mfma_f32_16x16x32_bf16(ah, bA[nt], acc[nt], 0, 0, 0);
        acc[nt] = __builtin_amdgcn_mfma_f32_16x16x32_bf16(al, bA[nt], acc[nt], 0, 0, 0);
      }
      if (kb + 2 < KB_) {
#pragma unroll
        for (int nt = 0; nt < NTC; ++nt)
          bA[nt] = *(const short8*)(bp + ((size_t)((kb + 2) * NTC + nt)) * 512);
      }
    }
    {
      short8 ah = *(const short8*)&hH[l15][(kb + 1) * 32 + quad * 8];
      short8 al = *(const short8*)&hL[l15][(kb + 1) * 32 + quad * 8];
#pragma unroll
      for (int nt = 0; nt < NTC; ++nt) {
        acc[nt] = __builtin_amdgcn_mfma_f32_16x16x32_bf16(ah, bB[nt], acc[nt], 0, 0, 0);
        acc[nt] = __builtin_amdgcn_mfma_f32_16x16x32_bf16(al, bB[nt], acc[nt], 0, 0, 0);
      }
      if (kb + 3 < KB_) {
#pragma unroll
        for (int nt = 0; nt < NTC; ++nt)
          bB[nt] = *(const short8*)(bp + ((size_t)((kb + 3) * NTC + nt)) * 512);
      }
    }
  }
  __builtin_amdgcn_s_setprio(0);
}

// ---------------- K4: GRU scan, 4 WGs x 16 batch rows per direction ----------------
template <bool XPF32>
__global__ __launch_bounds__(512, 2) void k_scan(const unsigned short* __restrict__ bpack,
                                                 const float* __restrict__ biasc,
                                                 const void* __restrict__ xp_all,
                                                 const int* __restrict__ lens,
                                                 const int* __restrict__ flags,
                                                 float* __restrict__ hfin,          // [2][64][304]
                                                 void* __restrict__ outraw) {
  __shared__ unsigned short sHi[2][16][HSP];   // parity double buffer
  __shared__ unsigned short sLo[2][16][HSP];
  __shared__ __align__(16) unsigned short sB[NRESF * 512];

  const int tid = threadIdx.x;
  const int mg = blockIdx.x;        // m-group: batch rows 16mg..16mg+15
  const int dir = blockIdx.y;
  const int wave = tid >> 6, lane = tid & 63;
  const int l15 = lane & 15, quad = lane >> 4;
  const int obf = flags[0];
  unsigned short* out16 = (unsigned short*)outraw;
  float* out32 = (float*)outraw;

  const int NBLK = (wave < 3) ? 3 : 2;
  const int NTCw = NBLK * 3;
  const int UB0w = (wave < 3) ? wave * 3 : 9 + (wave - 3) * 2;
  const int FB   = (wave < 3) ? wave * 90 : 270 + (wave - 3) * 60;
  const int RB   = (wave < 3) ? wave * 18 : 54 + (wave - 3) * 12;

  // zero both h parity buffers (incl. the k-pad region 300..327)
  {
    unsigned int* p0 = (unsigned int*)&sHi[0][0][0];
    unsigned int* p1 = (unsigned int*)&sLo[0][0][0];
    for (int i = tid; i < 2 * 16 * HSP / 2; i += 512) { p0[i] = 0u; p1[i] = 0u; }
  }
  // copy this wave's resident B frags (kb < KRES) into LDS
  {
    const unsigned short* src = bpack + ((size_t)dir * FRAGS_PER_DIR + FB) * 512 + lane * 8;
    unsigned short* dst = sB + (size_t)RB * 512 + lane * 8;
    for (int j = 0; j < KRES * NTCw; ++j)
      *(uint4*)(dst + (size_t)j * 512) = *(const uint4*)(src + (size_t)j * 512);
  }

  // per-lane epilogue ownership: rows quad*4+r, u-cols (UB0w+lb)*16 + l15
  int ucl[3]; bool cv[3];
  float bz[3], brg[3], bh[3];
  int xcol[3][3];
  {
    const float* brec = biasc + (size_t)dir * 2 * NU + NU;
#pragma unroll
    for (int lb = 0; lb < 3; ++lb) {
      int u = (UB0w + lb) * 16 + l15;
      bool v = (lb < NBLK) && (u < U_);
      cv[lb] = v;
      ucl[lb] = v ? u : 0;
      bz[lb] = brec[ucl[lb]]; brg[lb] = brec[U_ + ucl[lb]]; bh[lb] = brec[2 * U_ + ucl[lb]];
      xcol[lb][0] = ucl[lb]; xcol[lb][1] = U_ + ucl[lb]; xcol[lb][2] = 2 * U_ + ucl[lb];
    }
  }
  size_t xbase[4];
#pragma unroll
  for (int r = 0; r < 4; ++r)
    xbase[r] = ((size_t)dir * 65536 + (size_t)(mg * 16 + quad * 4 + r) * T_) * XPW;
  int mylen[4];
#pragma unroll
  for (int r = 0; r < 4; ++r) mylen[r] = lens[mg * 16 + quad * 4 + r];
  float hold[3][4];
#pragma unroll
  for (int lb = 0; lb < 3; ++lb)
#pragma unroll
    for (int r = 0; r < 4; ++r) hold[lb][r] = 0.f;

  __syncthreads();

  const unsigned short* bp = bpack + ((size_t)dir * FRAGS_PER_DIR + FB) * 512 + (size_t)lane * 8;
  const unsigned short* sBw = sB + (size_t)RB * 512 + (size_t)lane * 8;

#pragma unroll 1
  for (int s = 0; s < T_; ++s) {
    const int t = dir ? (T_ - 1 - s) : s;
    const int par = s & 1;

    floatx4 acc[9];
#pragma unroll
    for (int i = 0; i < 9; ++i) acc[i] = {0.f, 0.f, 0.f, 0.f};
    float X[3][3][4];
    if (wave < 3) phase<9, XPF32>(acc, X, bp, sBw, sHi[par], sLo[par], xp_all, xbase, t, xcol, l15, quad);
    else          phase<6, XPF32>(acc, X, bp, sBw, sHi[par], sLo[par], xp_all, xbase, t, xcol, l15, quad);

    // epilogue: register-only inputs; writes go to the par^1 buffer -> no
    // barrier needed between phase and epilogue.
    unsigned short (*nHi)[HSP] = sHi[par ^ 1];
    unsigned short (*nLo)[HSP] = sLo[par ^ 1];
#pragma unroll
    for (int r = 0; r < 4; ++r) {
      const int row = quad * 4 + r;
      const bool m = (t < mylen[r]);
      const size_t ob = ((size_t)(mg * 16 + row) * T_ + t) * 600 + (size_t)dir * U_;
#pragma unroll
      for (int lb = 0; lb < 3; ++lb) {
        float z  = sigm_f(X[lb][0][r] + acc[lb * 3 + 0][r] + bz[lb]);
        float rg = sigm_f(X[lb][1][r] + acc[lb * 3 + 1][r] + brg[lb]);
        float hh = tanh_f(X[lb][2][r] + rg * (acc[lb * 3 + 2][r] + bh[lb]));
        float hn = z * hold[lb][r] + (1.f - z) * hh;
        float hw = m ? hn : hold[lb][r];
        hold[lb][r] = hw;
        if (cv[lb]) {
          float y = m ? hn : 0.f;
          if (obf) out16[ob + ucl[lb]] = f2b(y); else out32[ob + ucl[lb]] = y;
          unsigned short hib = f2b(hw);
          nHi[row][ucl[lb]] = hib;
          nLo[row][ucl[lb]] = f2b(hw - b2f_bits(hib));
        }
      }
    }

    // single per-step barrier: drain LDS writes only (no vmcnt drain).
    asm volatile("s_waitcnt lgkmcnt(0)" ::: "memory");
    __builtin_amdgcn_s_barrier();
    __builtin_amdgcn_sched_barrier(0);
  }

  // final state straight from registers
#pragma unroll
  for (int lb = 0; lb < 3; ++lb) {
    if (!cv[lb]) continue;
#pragma unroll
    for (int r = 0; r < 4; ++r)
      hfin[((size_t)dir * B_ + mg * 16 + quad * 4 + r) * 304 + ucl[lb]] = hold[lb][r];
  }
}

// ---------------- K5: state = relu(concat(h_f,h_b) @ w_fc + b_fc) ----------------
__global__ __launch_bounds__(320) void k_state(const float* __restrict__ hfin,
                                               const unsigned short* __restrict__ wfcc,
                                               const float* __restrict__ bfcc,
                                               const int* __restrict__ flags,
                                               void* __restrict__ outraw) {
  int b = blockIdx.x, u = threadIdx.x;
  if (u >= U_) return;
  int obf = flags[0];
  float acc = bfcc[u];
  const float* hf = hfin + (size_t)b * 304;
  const float* hb = hfin + ((size_t)B_ + b) * 304;
  for (int k = 0; k < U_; ++k) acc = fmaf(hf[k], b2f_bits(wfcc[(size_t)k * U_ + u]), acc);
  for (int k = 0; k < U_; ++k) acc = fmaf(hb[k], b2f_bits(wfcc[(size_t)(U_ + k) * U_ + u]), acc);
  float v = fmaxf(acc, 0.f);
  size_t oi = (size_t)B_ * T_ * 600 + (size_t)b * U_ + u;
  if (obf) ((unsigned short*)outraw)[oi] = f2b(v);
  else     ((float*)outraw)[oi] = v;
}

extern "C" void kernel_launch(void* const* d_in, const int* in_sizes, int n_in,
                              void* d_out, int out_size, void* d_ws, size_t ws_size,
                              hipStream_t stream) {
  const void* x    = d_in[0];
  const void* mask = d_in[1];
  const void* kf   = d_in[2];
  const void* rkf  = d_in[3];
  const void* bfw  = d_in[4];
  const void* kb   = d_in[5];
  const void* rkb  = d_in[6];
  const void* bbw  = d_in[7];
  const void* wfc  = d_in[8];
  const void* bfc  = d_in[9];

  char* ws = (char*)d_ws;
  size_t off = 0;
  auto alloc = [&](size_t bytes) { void* p = ws + off; off += (bytes + 255) & ~(size_t)255; return p; };
  int* flags            = (int*)alloc(256);
  int* lens             = (int*)alloc(256);
  unsigned short* xpad  = (unsigned short*)alloc((size_t)65536 * KP * 2);
  unsigned short* kpad  = (unsigned short*)alloc((size_t)2 * KP * NP * 2);
  unsigned short* rkc   = (unsigned short*)alloc((size_t)2 * D_ * NU * 2);
  unsigned short* bpack = (unsigned short*)alloc((size_t)2 * FRAGS_PER_DIR * 512 * 2);
  float* biasc          = (float*)alloc((size_t)2 * 2 * NU * 4);
  unsigned short* wfcc  = (unsigned short*)alloc((size_t)2 * U_ * U_ * 2);
  float* bfcc           = (float*)alloc((size_t)U_ * 4);
  float* hfin           = (float*)alloc((size_t)2 * B_ * 304 * 4);
  void* xp = (void*)(ws + off);
  size_t need_f32 = off + (size_t)2 * 65536 * XPW * 4;
  bool xpf32 = ws_size >= need_f32;

  k_detect<<<dim3(1), dim3(64), 0, stream>>>((const unsigned int*)x, (const unsigned char*)mask, flags);
  k_lengths<<<dim3(B_), dim3(256), 0, stream>>>((const unsigned char*)mask, flags, lens);
  k_xpad<<<dim3(65536 * 40 / 256), dim3(256), 0, stream>>>(x, flags, xpad);
  k_wpad<<<dim3((2 * KP * NP + 255) / 256), dim3(256), 0, stream>>>(kf, kb, flags, kpad);
  k_prep<<<dim3((2 * D_ * NU + 255) / 256), dim3(256), 0, stream>>>(rkf, rkb, bfw, bbw, wfc, bfc,
                                                                    flags, rkc, biasc, wfcc, bfcc);
  k_bpack<<<dim3((2 * FRAGS_PER_DIR * 512 + 255) / 256), dim3(256), 0, stream>>>(rkc, bpack);
  if (xpf32) {
    k_gemm<true><<<dim3(1024, 15, 2), dim3(256), 0, stream>>>(xpad, kpad, biasc, xp);
    k_scan<true><<<dim3(NWGM, 2), dim3(512), 0, stream>>>(bpack, biasc, xp, lens, flags, hfin, d_out);
  } else {
    k_gemm<false><<<dim3(1024, 15, 2), dim3(256), 0, stream>>>(xpad, kpad, biasc, xp);
    k_scan<false><<<dim3(NWGM, 2), dim3(512), 0, stream>>>(bpack, biasc, xp, lens, flags, hfin, d_out);
  }
  k_state<<<dim3(B_), dim3(320), 0, stream>>>(hfin, wfcc, bfcc, flags, d_out);
}

// Round 4
// 15966.626 us; speedup vs baseline: 1.1651x; 1.1651x over previous
//
#include <hip/hip_runtime.h>
#include <hip/hip_bf16.h>

// Bidirectional GRU encoder, B=64 T=1024 D=300 U=300.
// Round 8: occupancy fix on the batch-split scan. R6/R7 ran 8 waves (2/SIMD)
// in a lockstep barrier loop -> ~60% stall (per-CU MfmaUtil 14%, VALUBusy 27%).
// Now 1024-thread WGs (16 waves = 4/SIMD) per m-group: 19 u-blocks split as
// 3 waves x 2 blocks + 13 waves x 1 block, NB is a compile-time template so
// each variant fits the 128-VGPR budget 4 waves/SIMD requires; the NB branch
// is hoisted OUTSIDE the T-loop (equal barrier counts per step).
// Kept from R7: parity double-buffered h in LDS -> ONE lgkmcnt-only raw
// s_barrier per step. Reverted from R7: sched_barrier(0) (m141 anti-pattern,
// order-pinning cost ~40%) and s_setprio (m190: hurts lockstep GEMM loops).

#define B_   64
#define T_   1024
#define D_   300
#define U_   300
#define NU   900      // 3U
#define KP   320      // padded K for input GEMM
#define NP   960      // padded N width of k_pad
#define XPW  912      // xp row stride (elements)
#define KB_  10       // K blocks of 32 (320/32)
#define KRES 2        // K blocks LDS-resident in scan
#define HSP  328      // h LDS row stride (shorts)
#define FRAGS_PER_DIR 570   // 3 waves*60 + 13 waves*30
#define NRESF 114           // resident frags per dir (3*12 + 13*6)
#define NWGM 4              // m-groups (16 rows each)

typedef short short8 __attribute__((ext_vector_type(8)));
typedef float floatx4 __attribute__((ext_vector_type(4)));

__device__ __forceinline__ float b2f_bits(unsigned short u) {
  union { unsigned int i; float f; } v; v.i = ((unsigned int)u) << 16; return v.f;
}
__device__ __forceinline__ unsigned short f2b(float f) {
  __hip_bfloat16 h = __float2bfloat16(f);  // RNE
  return *reinterpret_cast<unsigned short*>(&h);
}
__device__ __forceinline__ float sigm_f(float x) {
  float e = __expf(-x);
  return __fdividef(1.f, 1.f + e);
}
__device__ __forceinline__ float tanh_f(float x) {
  float e = __expf(2.f * x);
  return 1.f - __fdividef(2.f, e + 1.f);
}

// ---------------- K_detect: input dtype + mask dtype flags ----------------
__global__ __launch_bounds__(64) void k_detect(const unsigned int* __restrict__ xw,
                                               const unsigned char* __restrict__ mb,
                                               int* __restrict__ flags) {
  __shared__ int red[64];
  int tid = threadIdx.x;
  int hits = 0;
  for (int i = tid; i < 2048; i += 64) {
    unsigned int lo = xw[i] & 0xFFFFu;
    int e = (int)((lo >> 7) & 0xFF);
    if (e >= 105 && e <= 135) hits++;   // plausible bf16 exponent for N(0,1)
  }
  red[tid] = hits;
  __syncthreads();
  if (tid == 0) {
    int s = 0;
    for (int i = 0; i < 64; ++i) s += red[i];
    flags[0] = (s >= 1024) ? 1 : 0;
    unsigned char b0 = mb[0], b1 = mb[1];
    flags[1] = (b1 == 0) ? 0 : ((b0 == 1 && b1 == 1) ? 1 : 2);
  }
}

// ---------------- K0: lengths from mask ----------------
__global__ __launch_bounds__(256) void k_lengths(const unsigned char* __restrict__ mraw,
                                                 const int* __restrict__ flags,
                                                 int* __restrict__ lens) {
  __shared__ int red[256];
  int b = blockIdx.x, tid = threadIdx.x;
  int mt = flags[1];
  int s = 0;
  if (mt == 0) {
    const int* m = (const int*)mraw;
    for (int t = tid; t < T_; t += 256) s += m[(size_t)b * T_ + t] ? 1 : 0;
  } else if (mt == 1) {
    for (int t = tid; t < T_; t += 256) s += mraw[(size_t)b * T_ + t] ? 1 : 0;
  } else {
    const unsigned short* m = (const unsigned short*)mraw;
    for (int t = tid; t < T_; t += 256) s += m[(size_t)b * T_ + t] ? 1 : 0;
  }
  red[tid] = s; __syncthreads();
  for (int off = 128; off > 0; off >>= 1) {
    if (tid < off) red[tid] += red[tid + off];
    __syncthreads();
  }
  if (tid == 0) lens[b] = red[0];
}

// ---------------- K1: pad x -> [65536,320] bf16 ----------------
__global__ __launch_bounds__(256) void k_xpad(const void* __restrict__ xraw,
                                              const int* __restrict__ flags,
                                              unsigned short* __restrict__ xp) {
  int id = blockIdx.x * 256 + threadIdx.x;
  int row = id / 40, seg = id % 40;
  int kbase = seg * 8;
  int bf = flags[0];
  unsigned short v[8];
  if (bf) {
    const unsigned short* x = (const unsigned short*)xraw;
#pragma unroll
    for (int i = 0; i < 8; ++i) {
      int k = kbase + i;
      v[i] = (k < D_) ? x[(size_t)row * D_ + k] : (unsigned short)0;
    }
  } else {
    const float* x = (const float*)xraw;
#pragma unroll
    for (int i = 0; i < 8; ++i) {
      int k = kbase + i;
      v[i] = (k < D_) ? f2b(x[(size_t)row * D_ + k]) : (unsigned short)0;
    }
  }
  uint4 o;
  o.x = (unsigned)v[0] | ((unsigned)v[1] << 16);
  o.y = (unsigned)v[2] | ((unsigned)v[3] << 16);
  o.z = (unsigned)v[4] | ((unsigned)v[5] << 16);
  o.w = (unsigned)v[6] | ((unsigned)v[7] << 16);
  *(uint4*)(xp + (size_t)row * KP + kbase) = o;
}

// ---------------- K2: pad k_{fwd,bwd} -> [2][320,960] bf16 ----------------
__global__ __launch_bounds__(256) void k_wpad(const void* __restrict__ kf,
                                              const void* __restrict__ kb,
                                              const int* __restrict__ flags,
                                              unsigned short* __restrict__ kp) {
  int id = blockIdx.x * 256 + threadIdx.x;
  if (id >= 2 * KP * NP) return;
  int dir = id / (KP * NP);
  int r = id % (KP * NP);
  int k = r / NP, n = r % NP;
  int bf = flags[0];
  unsigned short v = 0;
  if (k < D_ && n < NU) {
    size_t si = (size_t)k * NU + n;
    if (bf) v = ((const unsigned short*)(dir ? kb : kf))[si];
    else    v = f2b(((const float*)(dir ? kb : kf))[si]);
  }
  kp[id] = v;
}

// ---------------- K_prep: canonical rk (bf16), biases (f32), wfc, bfc ----------------
__global__ __launch_bounds__(256) void k_prep(const void* __restrict__ rkf,
                                              const void* __restrict__ rkb,
                                              const void* __restrict__ bfw,
                                              const void* __restrict__ bbw,
                                              const void* __restrict__ wfc,
                                              const void* __restrict__ bfc,
                                              const int* __restrict__ flags,
                                              unsigned short* __restrict__ rkc,   // [2][300][900]
                                              float* __restrict__ biasc,          // [2][2][900]
                                              unsigned short* __restrict__ wfcc,  // [600][300]
                                              float* __restrict__ bfcc) {         // [300]
  int i = blockIdx.x * 256 + threadIdx.x;
  int bf = flags[0];
  if (i < 2 * D_ * NU) {
    int dir = i / (D_ * NU), r = i % (D_ * NU);
    const void* src = dir ? rkb : rkf;
    rkc[i] = bf ? ((const unsigned short*)src)[r] : f2b(((const float*)src)[r]);
  }
  if (i < 2 * 2 * NU) {
    int dir = i / (2 * NU), r = i % (2 * NU);
    const void* src = dir ? bbw : bfw;
    biasc[i] = bf ? b2f_bits(((const unsigned short*)src)[r]) : ((const float*)src)[r];
  }
  if (i < 2 * U_ * U_) {
    wfcc[i] = bf ? ((const unsigned short*)wfc)[i] : f2b(((const float*)wfc)[i]);
  }
  if (i < U_) {
    bfcc[i] = bf ? b2f_bits(((const unsigned short*)bfc)[i]) : ((const float*)bfc)[i];
  }
}

// ---------------- K_bpack: rk -> per-wave MFMA B-fragment stream ----------------
// 16-wave layout: waves 0-2 own 2 u-blocks (ub0 = 2w), waves 3-15 own 1
// (ub0 = 6 + (w-3)). 19 u-blocks of 16 cols cover u 0..303 (300..303 pad).
// n-tile nt = lb*3 + g (local block lb, gate g z/r/h).
// frag f = FB(w) + kb*NTC + nt; bpack[(dir*570+f)*512 + lane*8 + j] =
//   rk[k = kb*32 + (lane>>4)*8 + j][g*300 + (ub0+lb)*16 + (lane&15)], 0 if pad.
__global__ __launch_bounds__(256) void k_bpack(const unsigned short* __restrict__ rkc,
                                               unsigned short* __restrict__ bpack) {
  int idx = blockIdx.x * 256 + threadIdx.x;
  const int total = 2 * FRAGS_PER_DIR * 512;
  if (idx >= total) return;
  int rem = idx;
  int j = rem & 7; rem >>= 3;
  int lane = rem & 63; rem >>= 6;
  int f = rem % FRAGS_PER_DIR;
  int dir = rem / FRAGS_PER_DIR;
  int w, fr, ntc;
  if (f < 180) { w = f / 60; fr = f - w * 60; ntc = 6; }
  else { int f2 = f - 180; w = 3 + f2 / 30; fr = f2 % 30; ntc = 3; }
  int kb = fr / ntc, nt = fr % ntc;
  int lb = nt / 3, g = nt % 3;
  int ub0 = (w < 3) ? 2 * w : 6 + (w - 3);
  int l15 = lane & 15, quad = lane >> 4;
  int k = kb * 32 + quad * 8 + j;
  int u = (ub0 + lb) * 16 + l15;
  unsigned short v = 0;
  if (k < U_ && u < U_) {
    v = rkc[(size_t)dir * U_ * NU + (size_t)k * NU + (size_t)g * U_ + u];
  }
  bpack[idx] = v;
}

// ---------------- K3: xp = x @ k + b_in, MFMA 16x16x32 bf16 ----------------
template <bool XPF32>
__global__ __launch_bounds__(256) void k_gemm(const unsigned short* __restrict__ xpad,
                                              const unsigned short* __restrict__ kpad,
                                              const float* __restrict__ biasc,
                                              void* __restrict__ xp_out) {
  __shared__ __align__(16) unsigned short As[64 * 40];
  __shared__ __align__(16) unsigned short Bs[64 * 40];  // transposed: [n][k]
  int tid = threadIdx.x;
  int wave = tid >> 6, lane = tid & 63;
  int m0 = blockIdx.x * 64, n0 = blockIdx.y * 64;
  int dir = blockIdx.z;
  const unsigned short* Bsrc = kpad + (size_t)dir * KP * NP;
  const float* bin = biasc + (size_t)dir * 2 * NU;

  floatx4 acc[4];
#pragma unroll
  for (int i = 0; i < 4; ++i) acc[i] = {0.f, 0.f, 0.f, 0.f};

  int arow = tid >> 2, aseg = tid & 3;
  int bk = tid & 31, bn8 = (tid >> 5) * 8;
  int fr = lane & 15, fq = lane >> 4;

  for (int kc = 0; kc < KP; kc += 32) {
    uint4 av = *(const uint4*)(xpad + (size_t)(m0 + arow) * KP + kc + aseg * 8);
    uint4 bv = *(const uint4*)(Bsrc + (size_t)(kc + bk) * NP + n0 + bn8);
    *(uint4*)(As + arow * 40 + aseg * 8) = av;
    unsigned short tmp[8];
    tmp[0] = bv.x & 0xffff; tmp[1] = bv.x >> 16;
    tmp[2] = bv.y & 0xffff; tmp[3] = bv.y >> 16;
    tmp[4] = bv.z & 0xffff; tmp[5] = bv.z >> 16;
    tmp[6] = bv.w & 0xffff; tmp[7] = bv.w >> 16;
#pragma unroll
    for (int i = 0; i < 8; ++i) Bs[(bn8 + i) * 40 + bk] = tmp[i];
    __syncthreads();
    short8 a = *(const short8*)(As + (wave * 16 + fr) * 40 + fq * 8);
#pragma unroll
    for (int nt = 0; nt < 4; ++nt) {
      short8 bfrag = *(const short8*)(Bs + (nt * 16 + fr) * 40 + fq * 8);
      acc[nt] = __builtin_amdgcn_mfma_f32_16x16x32_bf16(a, bfrag, acc[nt], 0, 0, 0);
    }
    __syncthreads();
  }
#pragma unroll
  for (int nt = 0; nt < 4; ++nt) {
    int col = n0 + nt * 16 + fr;
    if (col >= XPW) continue;
    float bi = (col < NU) ? bin[col] : 0.f;
#pragma unroll
    for (int r = 0; r < 4; ++r) {
      int m = m0 + wave * 16 + fq * 4 + r;
      float v = acc[nt][r] + bi;
      size_t idx = ((size_t)dir * 65536 + m) * XPW + col;
      if (XPF32) ((float*)xp_out)[idx] = v;
      else ((unsigned short*)xp_out)[idx] = f2b(v);
    }
  }
}

// ---------------- K4: per-NB scan loop (whole T-loop, barrier inside) ----------------
template <int NB, bool XPF32>
__device__ __forceinline__ void scan_loop(
    const unsigned short* __restrict__ bp,    // wave's bpack base (+lane*8)
    const unsigned short* __restrict__ sBw,   // wave's resident LDS base (+lane*8)
    unsigned short (*sHiP)[16][HSP],          // [2 parity][16][HSP]
    unsigned short (*sLoP)[16][HSP],
    const void* __restrict__ xp_all,
    unsigned short* __restrict__ out16, float* __restrict__ out32, int obf,
    const float* __restrict__ brec, const int* __restrict__ lens,
    float* __restrict__ hfin,
    int dir, int mg, int ub0, int l15, int quad) {
  constexpr int NTC = NB * 3;

  // per-lane ownership: rows quad*4+r, u-cols (ub0+lb)*16 + l15
  int ucl[NB]; bool cv[NB];
  float bz[NB], brg[NB], bh[NB];
#pragma unroll
  for (int lb = 0; lb < NB; ++lb) {
    int u = (ub0 + lb) * 16 + l15;
    bool v = (u < U_);
    cv[lb] = v;
    ucl[lb] = v ? u : 0;
    bz[lb] = brec[ucl[lb]]; brg[lb] = brec[U_ + ucl[lb]]; bh[lb] = brec[2 * U_ + ucl[lb]];
  }
  size_t xbase[4];
#pragma unroll
  for (int r = 0; r < 4; ++r)
    xbase[r] = ((size_t)dir * 65536 + (size_t)(mg * 16 + quad * 4 + r) * T_) * XPW;
  int mylen[4];
#pragma unroll
  for (int r = 0; r < 4; ++r) mylen[r] = lens[mg * 16 + quad * 4 + r];
  float hold[NB][4];
#pragma unroll
  for (int lb = 0; lb < NB; ++lb)
#pragma unroll
    for (int r = 0; r < 4; ++r) hold[lb][r] = 0.f;

#pragma unroll 1
  for (int s = 0; s < T_; ++s) {
    const int t = dir ? (T_ - 1 - s) : s;
    const int par = s & 1;
    const unsigned short (*hH)[HSP] = sHiP[par];
    const unsigned short (*hL)[HSP] = sLoP[par];

    floatx4 acc[NTC];
#pragma unroll
    for (int i = 0; i < NTC; ++i) acc[i] = {0.f, 0.f, 0.f, 0.f};

    // issue first stream batch (kb = KRES), and (NB==1) the second too
    short8 bA[NTC];
#pragma unroll
    for (int nt = 0; nt < NTC; ++nt)
      bA[nt] = *(const short8*)(bp + ((size_t)(KRES * NTC + nt)) * 512);
    short8 bB[NB == 1 ? NTC : 1];
    if constexpr (NB == 1) {
#pragma unroll
      for (int nt = 0; nt < NTC; ++nt)
        bB[nt] = *(const short8*)(bp + ((size_t)((KRES + 1) * NTC + nt)) * 512);
    }

    // xp gate loads for this step (consumed in epilogue; covered by MFMA phase)
    float X[NB][3][4];
#pragma unroll
    for (int r = 0; r < 4; ++r) {
      size_t ro = xbase[r] + (size_t)t * XPW;
      if (XPF32) {
        const float* xr = (const float*)xp_all + ro;
#pragma unroll
        for (int lb = 0; lb < NB; ++lb) {
          X[lb][0][r] = xr[ucl[lb]];
          X[lb][1][r] = xr[U_ + ucl[lb]];
          X[lb][2][r] = xr[2 * U_ + ucl[lb]];
        }
      } else {
        const unsigned short* xr = (const unsigned short*)xp_all + ro;
#pragma unroll
        for (int lb = 0; lb < NB; ++lb) {
          X[lb][0][r] = b2f_bits(xr[ucl[lb]]);
          X[lb][1][r] = b2f_bits(xr[U_ + ucl[lb]]);
          X[lb][2][r] = b2f_bits(xr[2 * U_ + ucl[lb]]);
        }
      }
    }

    // LDS-resident kb = 0..KRES-1
#pragma unroll
    for (int kb = 0; kb < KRES; ++kb) {
      short8 ah = *(const short8*)&hH[l15][kb * 32 + quad * 8];
      short8 al = *(const short8*)&hL[l15][kb * 32 + quad * 8];
#pragma unroll
      for (int nt = 0; nt < NTC; ++nt) {
        short8 b = *(const short8*)(sBw + ((size_t)(kb * NTC + nt)) * 512);
        acc[nt] = __builtin_amdgcn_mfma_f32_16x16x32_bf16(ah, b, acc[nt], 0, 0, 0);
      }
#pragma unroll
      for (int nt = 0; nt < NTC; ++nt) {
        short8 b = *(const short8*)(sBw + ((size_t)(kb * NTC + nt)) * 512);
        acc[nt] = __builtin_amdgcn_mfma_f32_16x16x32_bf16(al, b, acc[nt], 0, 0, 0);
      }
    }

    // streamed kb = KRES..KB_-1
    if constexpr (NB == 1) {
      // double-buffered
#pragma unroll
      for (int kb = KRES; kb < KB_; kb += 2) {
        {
          short8 ah = *(const short8*)&hH[l15][kb * 32 + quad * 8];
          short8 al = *(const short8*)&hL[l15][kb * 32 + quad * 8];
#pragma unroll
          for (int nt = 0; nt < NTC; ++nt)
            acc[nt] = __builtin_amdgcn_mfma_f32_16x16x32_bf16(ah, bA[nt], acc[nt], 0, 0, 0);
#pragma unroll
          for (int nt = 0; nt < NTC; ++nt)
            acc[nt] = __builtin_amdgcn_mfma_f32_16x16x32_bf16(al, bA[nt], acc[nt], 0, 0, 0);
          if (kb + 2 < KB_) {
#pragma unroll
            for (int nt = 0; nt < NTC; ++nt)
              bA[nt] = *(const short8*)(bp + ((size_t)((kb + 2) * NTC + nt)) * 512);
          }
        }
        {
          short8 ah = *(const short8*)&hH[l15][(kb + 1) * 32 + quad * 8];
          short8 al = *(const short8*)&hL[l15][(kb + 1) * 32 + quad * 8];
#pragma unroll
          for (int nt = 0; nt < NTC; ++nt)
            acc[nt] = __builtin_amdgcn_mfma_f32_16x16x32_bf16(ah, bB[nt], acc[nt], 0, 0, 0);
#pragma unroll
          for (int nt = 0; nt < NTC; ++nt)
            acc[nt] = __builtin_amdgcn_mfma_f32_16x16x32_bf16(al, bB[nt], acc[nt], 0, 0, 0);
          if (kb + 3 < KB_) {
#pragma unroll
            for (int nt = 0; nt < NTC; ++nt)
              bB[nt] = *(const short8*)(bp + ((size_t)((kb + 3) * NTC + nt)) * 512);
          }
        }
      }
    } else {
      // single-buffered (keeps NB=2 waves under the 128-VGPR budget);
      // cross-wave overlap (4 waves/SIMD) hides the per-batch L2 latency.
#pragma unroll
      for (int kb = KRES; kb < KB_; ++kb) {
        short8 ah = *(const short8*)&hH[l15][kb * 32 + quad * 8];
        short8 al = *(const short8*)&hL[l15][kb * 32 + quad * 8];
#pragma unroll
        for (int nt = 0; nt < NTC; ++nt)
          acc[nt] = __builtin_amdgcn_mfma_f32_16x16x32_bf16(ah, bA[nt], acc[nt], 0, 0, 0);
#pragma unroll
        for (int nt = 0; nt < NTC; ++nt)
          acc[nt] = __builtin_amdgcn_mfma_f32_16x16x32_bf16(al, bA[nt], acc[nt], 0, 0, 0);
        if (kb + 1 < KB_) {
#pragma unroll
          for (int nt = 0; nt < NTC; ++nt)
            bA[nt] = *(const short8*)(bp + ((size_t)((kb + 1) * NTC + nt)) * 512);
        }
      }
    }

    // epilogue: register-only inputs; writes go to par^1 buffer.
    unsigned short (*nHi)[HSP] = sHiP[par ^ 1];
    unsigned short (*nLo)[HSP] = sLoP[par ^ 1];
#pragma unroll
    for (int r = 0; r < 4; ++r) {
      const int row = quad * 4 + r;
      const bool m = (t < mylen[r]);
      const size_t ob = ((size_t)(mg * 16 + row) * T_ + t) * 600 + (size_t)dir * U_;
#pragma unroll
      for (int lb = 0; lb < NB; ++lb) {
        float z  = sigm_f(X[lb][0][r] + acc[lb * 3 + 0][r] + bz[lb]);
        float rg = sigm_f(X[lb][1][r] + acc[lb * 3 + 1][r] + brg[lb]);
        float hh = tanh_f(X[lb][2][r] + rg * (acc[lb * 3 + 2][r] + bh[lb]));
        float hn = z * hold[lb][r] + (1.f - z) * hh;
        float hw = m ? hn : hold[lb][r];
        hold[lb][r] = hw;
        if (cv[lb]) {
          float y = m ? hn : 0.f;
          if (obf) out16[ob + ucl[lb]] = f2b(y); else out32[ob + ucl[lb]] = y;
          unsigned short hib = f2b(hw);
          nHi[row][ucl[lb]] = hib;
          nLo[row][ucl[lb]] = f2b(hw - b2f_bits(hib));
        }
      }
    }

    // single per-step barrier: drain LDS writes only (no vmcnt drain).
    asm volatile("s_waitcnt lgkmcnt(0)" ::: "memory");
    __builtin_amdgcn_s_barrier();
  }

  // final state straight from registers
#pragma unroll
  for (int lb = 0; lb < NB; ++lb) {
    if (!cv[lb]) continue;
#pragma unroll
    for (int r = 0; r < 4; ++r)
      hfin[((size_t)dir * B_ + mg * 16 + quad * 4 + r) * 304 + ucl[lb]] = hold[lb][r];
  }
}

// ---------------- K4: GRU scan, 4 WGs x 16 batch rows per direction ----------------
template <bool XPF32>
__global__ __launch_bounds__(1024, 1) void k_scan(const unsigned short* __restrict__ bpack,
                                                  const float* __restrict__ biasc,
                                                  const void* __restrict__ xp_all,
                                                  const int* __restrict__ lens,
                                                  const int* __restrict__ flags,
                                                  float* __restrict__ hfin,          // [2][64][304]
                                                  void* __restrict__ outraw) {
  __shared__ unsigned short sHi[2][16][HSP];   // parity double buffer
  __shared__ unsigned short sLo[2][16][HSP];
  __shared__ __align__(16) unsigned short sB[NRESF * 512];

  const int tid = threadIdx.x;
  const int mg = blockIdx.x;        // m-group: batch rows 16mg..16mg+15
  const int dir = blockIdx.y;
  const int wave = tid >> 6, lane = tid & 63;
  const int l15 = lane & 15, quad = lane >> 4;
  const int obf = flags[0];
  unsigned short* out16 = (unsigned short*)outraw;
  float* out32 = (float*)outraw;

  const int NBLK = (wave < 3) ? 2 : 1;
  const int NTCw = NBLK * 3;
  const int UB0w = (wave < 3) ? 2 * wave : 6 + (wave - 3);
  const int FB   = (wave < 3) ? wave * 60 : 180 + (wave - 3) * 30;
  const int RB   = (wave < 3) ? wave * 12 : 36 + (wave - 3) * 6;

  // zero both h parity buffers (incl. the k-pad region 300..327)
  {
    unsigned int* p0 = (unsigned int*)&sHi[0][0][0];
    unsigned int* p1 = (unsigned int*)&sLo[0][0][0];
    for (int i = tid; i < 2 * 16 * HSP / 2; i += 1024) { p0[i] = 0u; p1[i] = 0u; }
  }
  // copy this wave's resident B frags (kb < KRES) into LDS
  {
    const unsigned short* src = bpack + ((size_t)dir * FRAGS_PER_DIR + FB) * 512 + lane * 8;
    unsigned short* dst = sB + (size_t)RB * 512 + lane * 8;
    for (int j = 0; j < KRES * NTCw; ++j)
      *(uint4*)(dst + (size_t)j * 512) = *(const uint4*)(src + (size_t)j * 512);
  }
  __syncthreads();

  const unsigned short* bp = bpack + ((size_t)dir * FRAGS_PER_DIR + FB) * 512 + (size_t)lane * 8;
  const unsigned short* sBw = sB + (size_t)RB * 512 + (size_t)lane * 8;
  const float* brec = biasc + (size_t)dir * 2 * NU + NU;

  if (wave < 3)
    scan_loop<2, XPF32>(bp, sBw, sHi, sLo, xp_all, out16, out32, obf, brec, lens,
                        hfin, dir, mg, UB0w, l15, quad);
  else
    scan_loop<1, XPF32>(bp, sBw, sHi, sLo, xp_all, out16, out32, obf, brec, lens,
                        hfin, dir, mg, UB0w, l15, quad);
}

// ---------------- K5: state = relu(concat(h_f,h_b) @ w_fc + b_fc) ----------------
__global__ __launch_bounds__(320) void k_state(const float* __restrict__ hfin,
                                               const unsigned short* __restrict__ wfcc,
                                               const float* __restrict__ bfcc,
                                               const int* __restrict__ flags,
                                               void* __restrict__ outraw) {
  int b = blockIdx.x, u = threadIdx.x;
  if (u >= U_) return;
  int obf = flags[0];
  float acc = bfcc[u];
  const float* hf = hfin + (size_t)b * 304;
  const float* hb = hfin + ((size_t)B_ + b) * 304;
  for (int k = 0; k < U_; ++k) acc = fmaf(hf[k], b2f_bits(wfcc[(size_t)k * U_ + u]), acc);
  for (int k = 0; k < U_; ++k) acc = fmaf(hb[k], b2f_bits(wfcc[(size_t)(U_ + k) * U_ + u]), acc);
  float v = fmaxf(acc, 0.f);
  size_t oi = (size_t)B_ * T_ * 600 + (size_t)b * U_ + u;
  if (obf) ((unsigned short*)outraw)[oi] = f2b(v);
  else     ((float*)outraw)[oi] = v;
}

extern "C" void kernel_launch(void* const* d_in, const int* in_sizes, int n_in,
                              void* d_out, int out_size, void* d_ws, size_t ws_size,
                              hipStream_t stream) {
  const void* x    = d_in[0];
  const void* mask = d_in[1];
  const void* kf   = d_in[2];
  const void* rkf  = d_in[3];
  const void* bfw  = d_in[4];
  const void* kb   = d_in[5];
  const void* rkb  = d_in[6];
  const void* bbw  = d_in[7];
  const void* wfc  = d_in[8];
  const void* bfc  = d_in[9];

  char* ws = (char*)d_ws;
  size_t off = 0;
  auto alloc = [&](size_t bytes) { void* p = ws + off; off += (bytes + 255) & ~(size_t)255; return p; };
  int* flags            = (int*)alloc(256);
  int* lens             = (int*)alloc(256);
  unsigned short* xpad  = (unsigned short*)alloc((size_t)65536 * KP * 2);
  unsigned short* kpad  = (unsigned short*)alloc((size_t)2 * KP * NP * 2);
  unsigned short* rkc   = (unsigned short*)alloc((size_t)2 * D_ * NU * 2);
  unsigned short* bpack = (unsigned short*)alloc((size_t)2 * FRAGS_PER_DIR * 512 * 2);
  float* biasc          = (float*)alloc((size_t)2 * 2 * NU * 4);
  unsigned short* wfcc  = (unsigned short*)alloc((size_t)2 * U_ * U_ * 2);
  float* bfcc           = (float*)alloc((size_t)U_ * 4);
  float* hfin           = (float*)alloc((size_t)2 * B_ * 304 * 4);
  void* xp = (void*)(ws + off);
  size_t need_f32 = off + (size_t)2 * 65536 * XPW * 4;
  bool xpf32 = ws_size >= need_f32;

  k_detect<<<dim3(1), dim3(64), 0, stream>>>((const unsigned int*)x, (const unsigned char*)mask, flags);
  k_lengths<<<dim3(B_), dim3(256), 0, stream>>>((const unsigned char*)mask, flags, lens);
  k_xpad<<<dim3(65536 * 40 / 256), dim3(256), 0, stream>>>(x, flags, xpad);
  k_wpad<<<dim3((2 * KP * NP + 255) / 256), dim3(256), 0, stream>>>(kf, kb, flags, kpad);
  k_prep<<<dim3((2 * D_ * NU + 255) / 256), dim3(256), 0, stream>>>(rkf, rkb, bfw, bbw, wfc, bfc,
                                                                    flags, rkc, biasc, wfcc, bfcc);
  k_bpack<<<dim3((2 * FRAGS_PER_DIR * 512 + 255) / 256), dim3(256), 0, stream>>>(rkc, bpack);
  if (xpf32) {
    k_gemm<true><<<dim3(1024, 15, 2), dim3(256), 0, stream>>>(xpad, kpad, biasc, xp);
    k_scan<true><<<dim3(NWGM, 2), dim3(1024), 0, stream>>>(bpack, biasc, xp, lens, flags, hfin, d_out);
  } else {
    k_gemm<false><<<dim3(1024, 15, 2), dim3(256), 0, stream>>>(xpad, kpad, biasc, xp);
    k_scan<false><<<dim3(NWGM, 2), dim3(1024), 0, stream>>>(bpack, biasc, xp, lens, flags, hfin, d_out);
  }
  k_state<<<dim3(B_), dim3(320), 0, stream>>>(hfin, wfcc, bfcc, flags, d_out);
}

// Round 5
// 14693.217 us; speedup vs baseline: 1.2661x; 1.0867x over previous
//
#include <hip/hip_runtime.h>
#include <hip/hip_bf16.h>

// Bidirectional GRU encoder, B=64 T=1024 D=300 U=300.
// Round 9: R6 shape (8 waves, 2/SIMD, no spill) + deep L2 stream prefetch.
// R8 failed because 16 waves capped VGPR at 64 -> scratch spills (VALUBusy
// DOWN, time UP) and doubled LDS A-read traffic (bank conflicts 5.2M->10.5M).
// Here: 512 threads, launch_bounds(512,2) -> 256-VGPR budget; the B-stream
// uses a depth-3/4 circular register buffer (statically indexed, fully
// unrolled) so each wave has ~240-270 issue-cycles of L2 latency coverage;
// xp loads issued at step top (hidden under MFMA phase). Kept from R7:
// parity double-buffered h -> ONE lgkmcnt-only s_barrier per step.
// No sched_barrier(0), no setprio (measured poisons, R7).

#define B_   64
#define T_   1024
#define D_   300
#define U_   300
#define NU   900      // 3U
#define KP   320      // padded K for input GEMM
#define NP   960      // padded N width of k_pad
#define XPW  912      // xp row stride (elements)
#define KB_  10       // K blocks of 32 (320/32)
#define KRES 2        // K blocks LDS-resident in scan
#define HSP  328      // h LDS row stride (shorts): 656B -> 2-way-free bank stride
#define FRAGS_PER_DIR 570   // 3 waves*90 + 5 waves*60
#define NRESF 114           // resident frags per dir (3*18 + 5*12)
#define NWGM 4              // m-groups (16 rows each)

typedef short short8 __attribute__((ext_vector_type(8)));
typedef float floatx4 __attribute__((ext_vector_type(4)));

__device__ __forceinline__ float b2f_bits(unsigned short u) {
  union { unsigned int i; float f; } v; v.i = ((unsigned int)u) << 16; return v.f;
}
__device__ __forceinline__ unsigned short f2b(float f) {
  __hip_bfloat16 h = __float2bfloat16(f);  // RNE
  return *reinterpret_cast<unsigned short*>(&h);
}
__device__ __forceinline__ float sigm_f(float x) {
  float e = __expf(-x);
  return __fdividef(1.f, 1.f + e);
}
__device__ __forceinline__ float tanh_f(float x) {
  float e = __expf(2.f * x);
  return 1.f - __fdividef(2.f, e + 1.f);
}

// ---------------- K_detect: input dtype + mask dtype flags ----------------
__global__ __launch_bounds__(64) void k_detect(const unsigned int* __restrict__ xw,
                                               const unsigned char* __restrict__ mb,
                                               int* __restrict__ flags) {
  __shared__ int red[64];
  int tid = threadIdx.x;
  int hits = 0;
  for (int i = tid; i < 2048; i += 64) {
    unsigned int lo = xw[i] & 0xFFFFu;
    int e = (int)((lo >> 7) & 0xFF);
    if (e >= 105 && e <= 135) hits++;   // plausible bf16 exponent for N(0,1)
  }
  red[tid] = hits;
  __syncthreads();
  if (tid == 0) {
    int s = 0;
    for (int i = 0; i < 64; ++i) s += red[i];
    flags[0] = (s >= 1024) ? 1 : 0;
    unsigned char b0 = mb[0], b1 = mb[1];
    flags[1] = (b1 == 0) ? 0 : ((b0 == 1 && b1 == 1) ? 1 : 2);
  }
}

// ---------------- K0: lengths from mask ----------------
__global__ __launch_bounds__(256) void k_lengths(const unsigned char* __restrict__ mraw,
                                                 const int* __restrict__ flags,
                                                 int* __restrict__ lens) {
  __shared__ int red[256];
  int b = blockIdx.x, tid = threadIdx.x;
  int mt = flags[1];
  int s = 0;
  if (mt == 0) {
    const int* m = (const int*)mraw;
    for (int t = tid; t < T_; t += 256) s += m[(size_t)b * T_ + t] ? 1 : 0;
  } else if (mt == 1) {
    for (int t = tid; t < T_; t += 256) s += mraw[(size_t)b * T_ + t] ? 1 : 0;
  } else {
    const unsigned short* m = (const unsigned short*)mraw;
    for (int t = tid; t < T_; t += 256) s += m[(size_t)b * T_ + t] ? 1 : 0;
  }
  red[tid] = s; __syncthreads();
  for (int off = 128; off > 0; off >>= 1) {
    if (tid < off) red[tid] += red[tid + off];
    __syncthreads();
  }
  if (tid == 0) lens[b] = red[0];
}

// ---------------- K1: pad x -> [65536,320] bf16 ----------------
__global__ __launch_bounds__(256) void k_xpad(const void* __restrict__ xraw,
                                              const int* __restrict__ flags,
                                              unsigned short* __restrict__ xp) {
  int id = blockIdx.x * 256 + threadIdx.x;
  int row = id / 40, seg = id % 40;
  int kbase = seg * 8;
  int bf = flags[0];
  unsigned short v[8];
  if (bf) {
    const unsigned short* x = (const unsigned short*)xraw;
#pragma unroll
    for (int i = 0; i < 8; ++i) {
      int k = kbase + i;
      v[i] = (k < D_) ? x[(size_t)row * D_ + k] : (unsigned short)0;
    }
  } else {
    const float* x = (const float*)xraw;
#pragma unroll
    for (int i = 0; i < 8; ++i) {
      int k = kbase + i;
      v[i] = (k < D_) ? f2b(x[(size_t)row * D_ + k]) : (unsigned short)0;
    }
  }
  uint4 o;
  o.x = (unsigned)v[0] | ((unsigned)v[1] << 16);
  o.y = (unsigned)v[2] | ((unsigned)v[3] << 16);
  o.z = (unsigned)v[4] | ((unsigned)v[5] << 16);
  o.w = (unsigned)v[6] | ((unsigned)v[7] << 16);
  *(uint4*)(xp + (size_t)row * KP + kbase) = o;
}

// ---------------- K2: pad k_{fwd,bwd} -> [2][320,960] bf16 ----------------
__global__ __launch_bounds__(256) void k_wpad(const void* __restrict__ kf,
                                              const void* __restrict__ kb,
                                              const int* __restrict__ flags,
                                              unsigned short* __restrict__ kp) {
  int id = blockIdx.x * 256 + threadIdx.x;
  if (id >= 2 * KP * NP) return;
  int dir = id / (KP * NP);
  int r = id % (KP * NP);
  int k = r / NP, n = r % NP;
  int bf = flags[0];
  unsigned short v = 0;
  if (k < D_ && n < NU) {
    size_t si = (size_t)k * NU + n;
    if (bf) v = ((const unsigned short*)(dir ? kb : kf))[si];
    else    v = f2b(((const float*)(dir ? kb : kf))[si]);
  }
  kp[id] = v;
}

// ---------------- K_prep: canonical rk (bf16), biases (f32), wfc, bfc ----------------
__global__ __launch_bounds__(256) void k_prep(const void* __restrict__ rkf,
                                              const void* __restrict__ rkb,
                                              const void* __restrict__ bfw,
                                              const void* __restrict__ bbw,
                                              const void* __restrict__ wfc,
                                              const void* __restrict__ bfc,
                                              const int* __restrict__ flags,
                                              unsigned short* __restrict__ rkc,   // [2][300][900]
                                              float* __restrict__ biasc,          // [2][2][900]
                                              unsigned short* __restrict__ wfcc,  // [600][300]
                                              float* __restrict__ bfcc) {         // [300]
  int i = blockIdx.x * 256 + threadIdx.x;
  int bf = flags[0];
  if (i < 2 * D_ * NU) {
    int dir = i / (D_ * NU), r = i % (D_ * NU);
    const void* src = dir ? rkb : rkf;
    rkc[i] = bf ? ((const unsigned short*)src)[r] : f2b(((const float*)src)[r]);
  }
  if (i < 2 * 2 * NU) {
    int dir = i / (2 * NU), r = i % (2 * NU);
    const void* src = dir ? bbw : bfw;
    biasc[i] = bf ? b2f_bits(((const unsigned short*)src)[r]) : ((const float*)src)[r];
  }
  if (i < 2 * U_ * U_) {
    wfcc[i] = bf ? ((const unsigned short*)wfc)[i] : f2b(((const float*)wfc)[i]);
  }
  if (i < U_) {
    bfcc[i] = bf ? b2f_bits(((const unsigned short*)bfc)[i]) : ((const float*)bfc)[i];
  }
}

// ---------------- K_bpack: rk -> per-wave MFMA B-fragment stream ----------------
// 8-wave layout: waves 0-2 own 3 u-blocks (ub0 = 3w), waves 3-7 own 2
// (ub0 = 9 + 2(w-3)). 19 u-blocks of 16 cols cover u 0..303 (300..303 pad).
// n-tile nt = lb*3 + g. frag f = FB(w) + kb*NTC + nt.
__global__ __launch_bounds__(256) void k_bpack(const unsigned short* __restrict__ rkc,
                                               unsigned short* __restrict__ bpack) {
  int idx = blockIdx.x * 256 + threadIdx.x;
  const int total = 2 * FRAGS_PER_DIR * 512;
  if (idx >= total) return;
  int rem = idx;
  int j = rem & 7; rem >>= 3;
  int lane = rem & 63; rem >>= 6;
  int f = rem % FRAGS_PER_DIR;
  int dir = rem / FRAGS_PER_DIR;
  int w, fr, ntc;
  if (f < 270) { w = f / 90; fr = f - w * 90; ntc = 9; }
  else { int f2 = f - 270; w = 3 + f2 / 60; fr = f2 % 60; ntc = 6; }
  int kb = fr / ntc, nt = fr % ntc;
  int lb = nt / 3, g = nt % 3;
  int ub0 = (w < 3) ? w * 3 : 9 + (w - 3) * 2;
  int l15 = lane & 15, quad = lane >> 4;
  int k = kb * 32 + quad * 8 + j;
  int u = (ub0 + lb) * 16 + l15;
  unsigned short v = 0;
  if (k < U_ && u < U_) {
    v = rkc[(size_t)dir * U_ * NU + (size_t)k * NU + (size_t)g * U_ + u];
  }
  bpack[idx] = v;
}

// ---------------- K3: xp = x @ k + b_in, MFMA 16x16x32 bf16 ----------------
template <bool XPF32>
__global__ __launch_bounds__(256) void k_gemm(const unsigned short* __restrict__ xpad,
                                              const unsigned short* __restrict__ kpad,
                                              const float* __restrict__ biasc,
                                              void* __restrict__ xp_out) {
  __shared__ __align__(16) unsigned short As[64 * 40];
  __shared__ __align__(16) unsigned short Bs[64 * 40];  // transposed: [n][k]
  int tid = threadIdx.x;
  int wave = tid >> 6, lane = tid & 63;
  int m0 = blockIdx.x * 64, n0 = blockIdx.y * 64;
  int dir = blockIdx.z;
  const unsigned short* Bsrc = kpad + (size_t)dir * KP * NP;
  const float* bin = biasc + (size_t)dir * 2 * NU;

  floatx4 acc[4];
#pragma unroll
  for (int i = 0; i < 4; ++i) acc[i] = {0.f, 0.f, 0.f, 0.f};

  int arow = tid >> 2, aseg = tid & 3;
  int bk = tid & 31, bn8 = (tid >> 5) * 8;
  int fr = lane & 15, fq = lane >> 4;

  for (int kc = 0; kc < KP; kc += 32) {
    uint4 av = *(const uint4*)(xpad + (size_t)(m0 + arow) * KP + kc + aseg * 8);
    uint4 bv = *(const uint4*)(Bsrc + (size_t)(kc + bk) * NP + n0 + bn8);
    *(uint4*)(As + arow * 40 + aseg * 8) = av;
    unsigned short tmp[8];
    tmp[0] = bv.x & 0xffff; tmp[1] = bv.x >> 16;
    tmp[2] = bv.y & 0xffff; tmp[3] = bv.y >> 16;
    tmp[4] = bv.z & 0xffff; tmp[5] = bv.z >> 16;
    tmp[6] = bv.w & 0xffff; tmp[7] = bv.w >> 16;
#pragma unroll
    for (int i = 0; i < 8; ++i) Bs[(bn8 + i) * 40 + bk] = tmp[i];
    __syncthreads();
    short8 a = *(const short8*)(As + (wave * 16 + fr) * 40 + fq * 8);
#pragma unroll
    for (int nt = 0; nt < 4; ++nt) {
      short8 bfrag = *(const short8*)(Bs + (nt * 16 + fr) * 40 + fq * 8);
      acc[nt] = __builtin_amdgcn_mfma_f32_16x16x32_bf16(a, bfrag, acc[nt], 0, 0, 0);
    }
    __syncthreads();
  }
#pragma unroll
  for (int nt = 0; nt < 4; ++nt) {
    int col = n0 + nt * 16 + fr;
    if (col >= XPW) continue;
    float bi = (col < NU) ? bin[col] : 0.f;
#pragma unroll
    for (int r = 0; r < 4; ++r) {
      int m = m0 + wave * 16 + fq * 4 + r;
      float v = acc[nt][r] + bi;
      size_t idx = ((size_t)dir * 65536 + m) * XPW + col;
      if (XPF32) ((float*)xp_out)[idx] = v;
      else ((unsigned short*)xp_out)[idx] = f2b(v);
    }
  }
}

// ---------------- K4: per-wave scan loop (whole T-loop, barrier inside) ----------------
// NTC n-tiles per wave, D = stream prefetch depth (circular reg buffer,
// statically indexed via full unroll).
template <int NTC, int D, bool XPF32>
__device__ __forceinline__ void scan_loop(
    const unsigned short* __restrict__ bp,    // wave's bpack base (+lane*8)
    const unsigned short* __restrict__ sBw,   // wave's resident LDS base (+lane*8)
    unsigned short (*sHiP)[16][HSP],          // [2 parity][16][HSP]
    unsigned short (*sLoP)[16][HSP],
    const void* __restrict__ xp_all,
    unsigned short* __restrict__ out16, float* __restrict__ out32, int obf,
    const float* __restrict__ brec, const int* __restrict__ lens,
    float* __restrict__ hfin,
    int dir, int mg, int ub0, int l15, int quad) {
  constexpr int NB = NTC / 3;
  constexpr int NSTR = KB_ - KRES;   // streamed kb count (8)

  // per-lane ownership: rows quad*4+r, u-cols (ub0+lb)*16 + l15
  int ucl[NB]; bool cv[NB];
  float bz[NB], brg[NB], bh[NB];
#pragma unroll
  for (int lb = 0; lb < NB; ++lb) {
    int u = (ub0 + lb) * 16 + l15;
    bool v = (u < U_);
    cv[lb] = v;
    ucl[lb] = v ? u : 0;
    bz[lb] = brec[ucl[lb]]; brg[lb] = brec[U_ + ucl[lb]]; bh[lb] = brec[2 * U_ + ucl[lb]];
  }
  size_t xbase[4];
#pragma unroll
  for (int r = 0; r < 4; ++r)
    xbase[r] = ((size_t)dir * 65536 + (size_t)(mg * 16 + quad * 4 + r) * T_) * XPW;
  int mylen[4];
#pragma unroll
  for (int r = 0; r < 4; ++r) mylen[r] = lens[mg * 16 + quad * 4 + r];
  float hold[NB][4];
#pragma unroll
  for (int lb = 0; lb < NB; ++lb)
#pragma unroll
    for (int r = 0; r < 4; ++r) hold[lb][r] = 0.f;

#pragma unroll 1
  for (int s = 0; s < T_; ++s) {
    const int t = dir ? (T_ - 1 - s) : s;
    const int par = s & 1;
    const unsigned short (*hH)[HSP] = sHiP[par];
    const unsigned short (*hL)[HSP] = sLoP[par];

    floatx4 acc[NTC];
#pragma unroll
    for (int i = 0; i < NTC; ++i) acc[i] = {0.f, 0.f, 0.f, 0.f};

    // issue the first D stream batches (kb = KRES..KRES+D-1)
    short8 buf[D][NTC];
#pragma unroll
    for (int d = 0; d < D; ++d)
#pragma unroll
      for (int nt = 0; nt < NTC; ++nt)
        buf[d][nt] = *(const short8*)(bp + ((size_t)((KRES + d) * NTC + nt)) * 512);

    // xp gate loads for this step (consumed in epilogue; hidden under MFMAs)
    float X[NB][3][4];
#pragma unroll
    for (int r = 0; r < 4; ++r) {
      size_t ro = xbase[r] + (size_t)t * XPW;
      if (XPF32) {
        const float* xr = (const float*)xp_all + ro;
#pragma unroll
        for (int lb = 0; lb < NB; ++lb) {
          X[lb][0][r] = xr[ucl[lb]];
          X[lb][1][r] = xr[U_ + ucl[lb]];
          X[lb][2][r] = xr[2 * U_ + ucl[lb]];
        }
      } else {
        const unsigned short* xr = (const unsigned short*)xp_all + ro;
#pragma unroll
        for (int lb = 0; lb < NB; ++lb) {
          X[lb][0][r] = b2f_bits(xr[ucl[lb]]);
          X[lb][1][r] = b2f_bits(xr[U_ + ucl[lb]]);
          X[lb][2][r] = b2f_bits(xr[2 * U_ + ucl[lb]]);
        }
      }
    }

    // LDS-resident kb = 0..KRES-1 (covers the first stream batches' latency)
#pragma unroll
    for (int kb = 0; kb < KRES; ++kb) {
      short8 ah = *(const short8*)&hH[l15][kb * 32 + quad * 8];
      short8 al = *(const short8*)&hL[l15][kb * 32 + quad * 8];
#pragma unroll
      for (int nt = 0; nt < NTC; ++nt) {
        short8 b = *(const short8*)(sBw + ((size_t)(kb * NTC + nt)) * 512);
        acc[nt] = __builtin_amdgcn_mfma_f32_16x16x32_bf16(ah, b, acc[nt], 0, 0, 0);
      }
#pragma unroll
      for (int nt = 0; nt < NTC; ++nt) {
        short8 b = *(const short8*)(sBw + ((size_t)(kb * NTC + nt)) * 512);
        acc[nt] = __builtin_amdgcn_mfma_f32_16x16x32_bf16(al, b, acc[nt], 0, 0, 0);
      }
    }

    // streamed kb = KRES..KB_-1, depth-D circular buffer, static indices
#pragma unroll
    for (int i = 0; i < NSTR; ++i) {
      const int kb = KRES + i;
      short8 ah = *(const short8*)&hH[l15][kb * 32 + quad * 8];
      short8 al = *(const short8*)&hL[l15][kb * 32 + quad * 8];
#pragma unroll
      for (int nt = 0; nt < NTC; ++nt)
        acc[nt] = __builtin_amdgcn_mfma_f32_16x16x32_bf16(ah, buf[i % D][nt], acc[nt], 0, 0, 0);
#pragma unroll
      for (int nt = 0; nt < NTC; ++nt)
        acc[nt] = __builtin_amdgcn_mfma_f32_16x16x32_bf16(al, buf[i % D][nt], acc[nt], 0, 0, 0);
      if (i + D < NSTR) {
#pragma unroll
        for (int nt = 0; nt < NTC; ++nt)
          buf[i % D][nt] = *(const short8*)(bp + ((size_t)((kb + D) * NTC + nt)) * 512);
      }
    }

    // epilogue: register-only inputs; writes go to par^1 buffer.
    unsigned short (*nHi)[HSP] = sHiP[par ^ 1];
    unsigned short (*nLo)[HSP] = sLoP[par ^ 1];
#pragma unroll
    for (int r = 0; r < 4; ++r) {
      const int row = quad * 4 + r;
      const bool m = (t < mylen[r]);
      const size_t ob = ((size_t)(mg * 16 + row) * T_ + t) * 600 + (size_t)dir * U_;
#pragma unroll
      for (int lb = 0; lb < NB; ++lb) {
        float z  = sigm_f(X[lb][0][r] + acc[lb * 3 + 0][r] + bz[lb]);
        float rg = sigm_f(X[lb][1][r] + acc[lb * 3 + 1][r] + brg[lb]);
        float hh = tanh_f(X[lb][2][r] + rg * (acc[lb * 3 + 2][r] + bh[lb]));
        float hn = z * hold[lb][r] + (1.f - z) * hh;
        float hw = m ? hn : hold[lb][r];
        hold[lb][r] = hw;
        if (cv[lb]) {
          float y = m ? hn : 0.f;
          if (obf) out16[ob + ucl[lb]] = f2b(y); else out32[ob + ucl[lb]] = y;
          unsigned short hib = f2b(hw);
          nHi[row][ucl[lb]] = hib;
          nLo[row][ucl[lb]] = f2b(hw - b2f_bits(hib));
        }
      }
    }

    // single per-step barrier: drain LDS ops only (no vmcnt drain).
    asm volatile("s_waitcnt lgkmcnt(0)" ::: "memory");
    __builtin_amdgcn_s_barrier();
  }

  // final state straight from registers
#pragma unroll
  for (int lb = 0; lb < NB; ++lb) {
    if (!cv[lb]) continue;
#pragma unroll
    for (int r = 0; r < 4; ++r)
      hfin[((size_t)dir * B_ + mg * 16 + quad * 4 + r) * 304 + ucl[lb]] = hold[lb][r];
  }
}

// ---------------- K4: GRU scan, 4 WGs x 16 batch rows per direction ----------------
template <bool XPF32>
__global__ __launch_bounds__(512, 2) void k_scan(const unsigned short* __restrict__ bpack,
                                                 const float* __restrict__ biasc,
                                                 const void* __restrict__ xp_all,
                                                 const int* __restrict__ lens,
                                                 const int* __restrict__ flags,
                                                 float* __restrict__ hfin,          // [2][64][304]
                                                 void* __restrict__ outraw) {
  __shared__ unsigned short sHi[2][16][HSP];   // parity double buffer
  __shared__ unsigned short sLo[2][16][HSP];
  __shared__ __align__(16) unsigned short sB[NRESF * 512];

  const int tid = threadIdx.x;
  const int mg = blockIdx.x;        // m-group: batch rows 16mg..16mg+15
  const int dir = blockIdx.y;
  const int wave = tid >> 6, lane = tid & 63;
  const int l15 = lane & 15, quad = lane >> 4;
  const int obf = flags[0];
  unsigned short* out16 = (unsigned short*)outraw;
  float* out32 = (float*)outraw;

  const int NTCw = (wave < 3) ? 9 : 6;
  const int UB0w = (wave < 3) ? wave * 3 : 9 + (wave - 3) * 2;
  const int FB   = (wave < 3) ? wave * 90 : 270 + (wave - 3) * 60;
  const int RB   = (wave < 3) ? wave * 18 : 54 + (wave - 3) * 12;

  // zero both h parity buffers (incl. the k-pad region 300..327)
  {
    unsigned int* p0 = (unsigned int*)&sHi[0][0][0];
    unsigned int* p1 = (unsigned int*)&sLo[0][0][0];
    for (int i = tid; i < 2 * 16 * HSP / 2; i += 512) { p0[i] = 0u; p1[i] = 0u; }
  }
  // copy this wave's resident B frags (kb < KRES) into LDS
  {
    const unsigned short* src = bpack + ((size_t)dir * FRAGS_PER_DIR + FB) * 512 + lane * 8;
    unsigned short* dst = sB + (size_t)RB * 512 + lane * 8;
    for (int j = 0; j < KRES * NTCw; ++j)
      *(uint4*)(dst + (size_t)j * 512) = *(const uint4*)(src + (size_t)j * 512);
  }
  __syncthreads();

  const unsigned short* bp = bpack + ((size_t)dir * FRAGS_PER_DIR + FB) * 512 + (size_t)lane * 8;
  const unsigned short* sBw = sB + (size_t)RB * 512 + (size_t)lane * 8;
  const float* brec = biasc + (size_t)dir * 2 * NU + NU;

  if (wave < 3)
    scan_loop<9, 3, XPF32>(bp, sBw, sHi, sLo, xp_all, out16, out32, obf, brec, lens,
                           hfin, dir, mg, UB0w, l15, quad);
  else
    scan_loop<6, 4, XPF32>(bp, sBw, sHi, sLo, xp_all, out16, out32, obf, brec, lens,
                           hfin, dir, mg, UB0w, l15, quad);
}

// ---------------- K5: state = relu(concat(h_f,h_b) @ w_fc + b_fc) ----------------
__global__ __launch_bounds__(320) void k_state(const float* __restrict__ hfin,
                                               const unsigned short* __restrict__ wfcc,
                                               const float* __restrict__ bfcc,
                                               const int* __restrict__ flags,
                                               void* __restrict__ outraw) {
  int b = blockIdx.x, u = threadIdx.x;
  if (u >= U_) return;
  int obf = flags[0];
  float acc = bfcc[u];
  const float* hf = hfin + (size_t)b * 304;
  const float* hb = hfin + ((size_t)B_ + b) * 304;
  for (int k = 0; k < U_; ++k) acc = fmaf(hf[k], b2f_bits(wfcc[(size_t)k * U_ + u]), acc);
  for (int k = 0; k < U_; ++k) acc = fmaf(hb[k], b2f_bits(wfcc[(size_t)(U_ + k) * U_ + u]), acc);
  float v = fmaxf(acc, 0.f);
  size_t oi = (size_t)B_ * T_ * 600 + (size_t)b * U_ + u;
  if (obf) ((unsigned short*)outraw)[oi] = f2b(v);
  else     ((float*)outraw)[oi] = v;
}

extern "C" void kernel_launch(void* const* d_in, const int* in_sizes, int n_in,
                              void* d_out, int out_size, void* d_ws, size_t ws_size,
                              hipStream_t stream) {
  const void* x    = d_in[0];
  const void* mask = d_in[1];
  const void* kf   = d_in[2];
  const void* rkf  = d_in[3];
  const void* bfw  = d_in[4];
  const void* kb   = d_in[5];
  const void* rkb  = d_in[6];
  const void* bbw  = d_in[7];
  const void* wfc  = d_in[8];
  const void* bfc  = d_in[9];

  char* ws = (char*)d_ws;
  size_t off = 0;
  auto alloc = [&](size_t bytes) { void* p = ws + off; off += (bytes + 255) & ~(size_t)255; return p; };
  int* flags            = (int*)alloc(256);
  int* lens             = (int*)alloc(256);
  unsigned short* xpad  = (unsigned short*)alloc((size_t)65536 * KP * 2);
  unsigned short* kpad  = (unsigned short*)alloc((size_t)2 * KP * NP * 2);
  unsigned short* rkc   = (unsigned short*)alloc((size_t)2 * D_ * NU * 2);
  unsigned short* bpack = (unsigned short*)alloc((size_t)2 * FRAGS_PER_DIR * 512 * 2);
  float* biasc          = (float*)alloc((size_t)2 * 2 * NU * 4);
  unsigned short* wfcc  = (unsigned short*)alloc((size_t)2 * U_ * U_ * 2);
  float* bfcc           = (float*)alloc((size_t)U_ * 4);
  float* hfin           = (float*)alloc((size_t)2 * B_ * 304 * 4);
  void* xp = (void*)(ws + off);
  size_t need_f32 = off + (size_t)2 * 65536 * XPW * 4;
  bool xpf32 = ws_size >= need_f32;

  k_detect<<<dim3(1), dim3(64), 0, stream>>>((const unsigned int*)x, (const unsigned char*)mask, flags);
  k_lengths<<<dim3(B_), dim3(256), 0, stream>>>((const unsigned char*)mask, flags, lens);
  k_xpad<<<dim3(65536 * 40 / 256), dim3(256), 0, stream>>>(x, flags, xpad);
  k_wpad<<<dim3((2 * KP * NP + 255) / 256), dim3(256), 0, stream>>>(kf, kb, flags, kpad);
  k_prep<<<dim3((2 * D_ * NU + 255) / 256), dim3(256), 0, stream>>>(rkf, rkb, bfw, bbw, wfc, bfc,
                                                                    flags, rkc, biasc, wfcc, bfcc);
  k_bpack<<<dim3((2 * FRAGS_PER_DIR * 512 + 255) / 256), dim3(256), 0, stream>>>(rkc, bpack);
  if (xpf32) {
    k_gemm<true><<<dim3(1024, 15, 2), dim3(256), 0, stream>>>(xpad, kpad, biasc, xp);
    k_scan<true><<<dim3(NWGM, 2), dim3(512), 0, stream>>>(bpack, biasc, xp, lens, flags, hfin, d_out);
  } else {
    k_gemm<false><<<dim3(1024, 15, 2), dim3(256), 0, stream>>>(xpad, kpad, biasc, xp);
    k_scan<false><<<dim3(NWGM, 2), dim3(512), 0, stream>>>(bpack, biasc, xp, lens, flags, hfin, d_out);
  }
  k_state<<<dim3(B_), dim3(320), 0, stream>>>(hfin, wfcc, bfcc, flags, d_out);
}

// Round 6
// 14587.393 us; speedup vs baseline: 1.2752x; 1.0073x over previous
//
#include <hip/hip_runtime.h>
#include <hip/hip_bf16.h>

// Bidirectional GRU encoder, B=64 T=1024 D=300 U=300.
// Round 10: DMA-streamed recurrent weights. R6-R9 all plateau at ~13.5-15.5
// us/step because the B-stream via register loads is outstanding-load-capped
// (~4KB in flight/CU at 2 waves/SIMD -> ~10-15 B/cyc effective vs the 24KB
// Little's-law requirement) -- register prefetch depth is irrelevant (R9:
// compiler sank the loads, dur unchanged). Fix: global_load_lds DMA into a
// 2-slot LDS window (2x57KB) with counted vmcnt(NTC) waits (T3/T4): LDS-
// destined loads hold no VGPRs so many stay in flight. Extras:
// - kb sweep direction alternates per step (0->9 / 9->0): the two slots at
//   step end hold the next step's first two kbs -> 2 kbs/step reused free,
//   stall-free step start.
// - xp gate loads prefetched ONE STEP ahead (issued after the final vmcnt(0),
//   raw bits in regs) so mid-sweep counted waits never drain HBM loads.
// - Parity double-buffered h in LDS -> one lgkmcnt-only s_barrier per step.

#define B_   64
#define T_   1024
#define D_   300
#define U_   300
#define NU   900      // 3U
#define KP   320      // padded K for input GEMM
#define NP   960      // padded N width of k_pad
#define XPW  912      // xp row stride (elements)
#define KB_  10       // K blocks of 32 (320/32)
#define HSP  328      // h LDS row stride (shorts)
#define FRAGS_PER_DIR 570   // 3 waves*90 + 5 waves*60
#define SLOTF 57            // frags per kb per WG (3*9 + 5*6)
#define SLOTSH (SLOTF*512)  // shorts per window slot
#define NWGM 4              // m-groups (16 rows each)

typedef short short8 __attribute__((ext_vector_type(8)));
typedef float floatx4 __attribute__((ext_vector_type(4)));

template <bool V> struct BoolC { static constexpr bool value = V; };

__device__ __forceinline__ float b2f_bits(unsigned short u) {
  union { unsigned int i; float f; } v; v.i = ((unsigned int)u) << 16; return v.f;
}
__device__ __forceinline__ unsigned short f2b(float f) {
  __hip_bfloat16 h = __float2bfloat16(f);  // RNE
  return *reinterpret_cast<unsigned short*>(&h);
}
__device__ __forceinline__ float sigm_f(float x) {
  float e = __expf(-x);
  return __fdividef(1.f, 1.f + e);
}
__device__ __forceinline__ float tanh_f(float x) {
  float e = __expf(2.f * x);
  return 1.f - __fdividef(2.f, e + 1.f);
}
__device__ __forceinline__ void wait_lgkm0() {
  asm volatile("s_waitcnt lgkmcnt(0)" ::: "memory");
}
template <int N> __device__ __forceinline__ void wait_vm() {
  asm volatile("s_waitcnt vmcnt(%0)" :: "n"(N) : "memory");
}
// async global->LDS DMA, 16B/lane: writes lds_base + lane*16 (wave-uniform base)
__device__ __forceinline__ void dma16(const unsigned short* g, unsigned short* l) {
  __builtin_amdgcn_global_load_lds(
      (const __attribute__((address_space(1))) unsigned int*)g,
      (__attribute__((address_space(3))) unsigned int*)l, 16, 0, 0);
}

// ---------------- K_detect: input dtype + mask dtype flags ----------------
__global__ __launch_bounds__(64) void k_detect(const unsigned int* __restrict__ xw,
                                               const unsigned char* __restrict__ mb,
                                               int* __restrict__ flags) {
  __shared__ int red[64];
  int tid = threadIdx.x;
  int hits = 0;
  for (int i = tid; i < 2048; i += 64) {
    unsigned int lo = xw[i] & 0xFFFFu;
    int e = (int)((lo >> 7) & 0xFF);
    if (e >= 105 && e <= 135) hits++;   // plausible bf16 exponent for N(0,1)
  }
  red[tid] = hits;
  __syncthreads();
  if (tid == 0) {
    int s = 0;
    for (int i = 0; i < 64; ++i) s += red[i];
    flags[0] = (s >= 1024) ? 1 : 0;
    unsigned char b0 = mb[0], b1 = mb[1];
    flags[1] = (b1 == 0) ? 0 : ((b0 == 1 && b1 == 1) ? 1 : 2);
  }
}

// ---------------- K0: lengths from mask ----------------
__global__ __launch_bounds__(256) void k_lengths(const unsigned char* __restrict__ mraw,
                                                 const int* __restrict__ flags,
                                                 int* __restrict__ lens) {
  __shared__ int red[256];
  int b = blockIdx.x, tid = threadIdx.x;
  int mt = flags[1];
  int s = 0;
  if (mt == 0) {
    const int* m = (const int*)mraw;
    for (int t = tid; t < T_; t += 256) s += m[(size_t)b * T_ + t] ? 1 : 0;
  } else if (mt == 1) {
    for (int t = tid; t < T_; t += 256) s += mraw[(size_t)b * T_ + t] ? 1 : 0;
  } else {
    const unsigned short* m = (const unsigned short*)mraw;
    for (int t = tid; t < T_; t += 256) s += m[(size_t)b * T_ + t] ? 1 : 0;
  }
  red[tid] = s; __syncthreads();
  for (int off = 128; off > 0; off >>= 1) {
    if (tid < off) red[tid] += red[tid + off];
    __syncthreads();
  }
  if (tid == 0) lens[b] = red[0];
}

// ---------------- K1: pad x -> [65536,320] bf16 ----------------
__global__ __launch_bounds__(256) void k_xpad(const void* __restrict__ xraw,
                                              const int* __restrict__ flags,
                                              unsigned short* __restrict__ xp) {
  int id = blockIdx.x * 256 + threadIdx.x;
  int row = id / 40, seg = id % 40;
  int kbase = seg * 8;
  int bf = flags[0];
  unsigned short v[8];
  if (bf) {
    const unsigned short* x = (const unsigned short*)xraw;
#pragma unroll
    for (int i = 0; i < 8; ++i) {
      int k = kbase + i;
      v[i] = (k < D_) ? x[(size_t)row * D_ + k] : (unsigned short)0;
    }
  } else {
    const float* x = (const float*)xraw;
#pragma unroll
    for (int i = 0; i < 8; ++i) {
      int k = kbase + i;
      v[i] = (k < D_) ? f2b(x[(size_t)row * D_ + k]) : (unsigned short)0;
    }
  }
  uint4 o;
  o.x = (unsigned)v[0] | ((unsigned)v[1] << 16);
  o.y = (unsigned)v[2] | ((unsigned)v[3] << 16);
  o.z = (unsigned)v[4] | ((unsigned)v[5] << 16);
  o.w = (unsigned)v[6] | ((unsigned)v[7] << 16);
  *(uint4*)(xp + (size_t)row * KP + kbase) = o;
}

// ---------------- K2: pad k_{fwd,bwd} -> [2][320,960] bf16 ----------------
__global__ __launch_bounds__(256) void k_wpad(const void* __restrict__ kf,
                                              const void* __restrict__ kb,
                                              const int* __restrict__ flags,
                                              unsigned short* __restrict__ kp) {
  int id = blockIdx.x * 256 + threadIdx.x;
  if (id >= 2 * KP * NP) return;
  int dir = id / (KP * NP);
  int r = id % (KP * NP);
  int k = r / NP, n = r % NP;
  int bf = flags[0];
  unsigned short v = 0;
  if (k < D_ && n < NU) {
    size_t si = (size_t)k * NU + n;
    if (bf) v = ((const unsigned short*)(dir ? kb : kf))[si];
    else    v = f2b(((const float*)(dir ? kb : kf))[si]);
  }
  kp[id] = v;
}

// ---------------- K_prep: canonical rk (bf16), biases (f32), wfc, bfc ----------------
__global__ __launch_bounds__(256) void k_prep(const void* __restrict__ rkf,
                                              const void* __restrict__ rkb,
                                              const void* __restrict__ bfw,
                                              const void* __restrict__ bbw,
                                              const void* __restrict__ wfc,
                                              const void* __restrict__ bfc,
                                              const int* __restrict__ flags,
                                              unsigned short* __restrict__ rkc,   // [2][300][900]
                                              float* __restrict__ biasc,          // [2][2][900]
                                              unsigned short* __restrict__ wfcc,  // [600][300]
                                              float* __restrict__ bfcc) {         // [300]
  int i = blockIdx.x * 256 + threadIdx.x;
  int bf = flags[0];
  if (i < 2 * D_ * NU) {
    int dir = i / (D_ * NU), r = i % (D_ * NU);
    const void* src = dir ? rkb : rkf;
    rkc[i] = bf ? ((const unsigned short*)src)[r] : f2b(((const float*)src)[r]);
  }
  if (i < 2 * 2 * NU) {
    int dir = i / (2 * NU), r = i % (2 * NU);
    const void* src = dir ? bbw : bfw;
    biasc[i] = bf ? b2f_bits(((const unsigned short*)src)[r]) : ((const float*)src)[r];
  }
  if (i < 2 * U_ * U_) {
    wfcc[i] = bf ? ((const unsigned short*)wfc)[i] : f2b(((const float*)wfc)[i]);
  }
  if (i < U_) {
    bfcc[i] = bf ? b2f_bits(((const unsigned short*)bfc)[i]) : ((const float*)bfc)[i];
  }
}

// ---------------- K_bpack: rk -> per-wave MFMA B-fragment stream ----------------
// 8-wave layout: waves 0-2 own 3 u-blocks (ub0 = 3w, NTC=9), waves 3-7 own 2
// (ub0 = 9+2(w-3), NTC=6). frag f = FB(w) + kb*NTC + nt, nt = lb*3 + g.
__global__ __launch_bounds__(256) void k_bpack(const unsigned short* __restrict__ rkc,
                                               unsigned short* __restrict__ bpack) {
  int idx = blockIdx.x * 256 + threadIdx.x;
  const int total = 2 * FRAGS_PER_DIR * 512;
  if (idx >= total) return;
  int rem = idx;
  int j = rem & 7; rem >>= 3;
  int lane = rem & 63; rem >>= 6;
  int f = rem % FRAGS_PER_DIR;
  int dir = rem / FRAGS_PER_DIR;
  int w, fr, ntc;
  if (f < 270) { w = f / 90; fr = f - w * 90; ntc = 9; }
  else { int f2 = f - 270; w = 3 + f2 / 60; fr = f2 % 60; ntc = 6; }
  int kb = fr / ntc, nt = fr % ntc;
  int lb = nt / 3, g = nt % 3;
  int ub0 = (w < 3) ? w * 3 : 9 + (w - 3) * 2;
  int l15 = lane & 15, quad = lane >> 4;
  int k = kb * 32 + quad * 8 + j;
  int u = (ub0 + lb) * 16 + l15;
  unsigned short v = 0;
  if (k < U_ && u < U_) {
    v = rkc[(size_t)dir * U_ * NU + (size_t)k * NU + (size_t)g * U_ + u];
  }
  bpack[idx] = v;
}

// ---------------- K3: xp = x @ k + b_in, MFMA 16x16x32 bf16 ----------------
template <bool XPF32>
__global__ __launch_bounds__(256) void k_gemm(const unsigned short* __restrict__ xpad,
                                              const unsigned short* __restrict__ kpad,
                                              const float* __restrict__ biasc,
                                              void* __restrict__ xp_out) {
  __shared__ __align__(16) unsigned short As[64 * 40];
  __shared__ __align__(16) unsigned short Bs[64 * 40];  // transposed: [n][k]
  int tid = threadIdx.x;
  int wave = tid >> 6, lane = tid & 63;
  int m0 = blockIdx.x * 64, n0 = blockIdx.y * 64;
  int dir = blockIdx.z;
  const unsigned short* Bsrc = kpad + (size_t)dir * KP * NP;
  const float* bin = biasc + (size_t)dir * 2 * NU;

  floatx4 acc[4];
#pragma unroll
  for (int i = 0; i < 4; ++i) acc[i] = {0.f, 0.f, 0.f, 0.f};

  int arow = tid >> 2, aseg = tid & 3;
  int bk = tid & 31, bn8 = (tid >> 5) * 8;
  int fr = lane & 15, fq = lane >> 4;

  for (int kc = 0; kc < KP; kc += 32) {
    uint4 av = *(const uint4*)(xpad + (size_t)(m0 + arow) * KP + kc + aseg * 8);
    uint4 bv = *(const uint4*)(Bsrc + (size_t)(kc + bk) * NP + n0 + bn8);
    *(uint4*)(As + arow * 40 + aseg * 8) = av;
    unsigned short tmp[8];
    tmp[0] = bv.x & 0xffff; tmp[1] = bv.x >> 16;
    tmp[2] = bv.y & 0xffff; tmp[3] = bv.y >> 16;
    tmp[4] = bv.z & 0xffff; tmp[5] = bv.z >> 16;
    tmp[6] = bv.w & 0xffff; tmp[7] = bv.w >> 16;
#pragma unroll
    for (int i = 0; i < 8; ++i) Bs[(bn8 + i) * 40 + bk] = tmp[i];
    __syncthreads();
    short8 a = *(const short8*)(As + (wave * 16 + fr) * 40 + fq * 8);
#pragma unroll
    for (int nt = 0; nt < 4; ++nt) {
      short8 bfrag = *(const short8*)(Bs + (nt * 16 + fr) * 40 + fq * 8);
      acc[nt] = __builtin_amdgcn_mfma_f32_16x16x32_bf16(a, bfrag, acc[nt], 0, 0, 0);
    }
    __syncthreads();
  }
#pragma unroll
  for (int nt = 0; nt < 4; ++nt) {
    int col = n0 + nt * 16 + fr;
    if (col >= XPW) continue;
    float bi = (col < NU) ? bin[col] : 0.f;
#pragma unroll
    for (int r = 0; r < 4; ++r) {
      int m = m0 + wave * 16 + fq * 4 + r;
      float v = acc[nt][r] + bi;
      size_t idx = ((size_t)dir * 65536 + m) * XPW + col;
      if (XPF32) ((float*)xp_out)[idx] = v;
      else ((unsigned short*)xp_out)[idx] = f2b(v);
    }
  }
}

// ---------------- K4: per-wave scan loop (DMA window, whole T-loop) ----------------
template <int NTC, bool XPF32>
__device__ __forceinline__ void scan_loop(
    const unsigned short* __restrict__ bpL,   // per-lane DMA src base (+lane*8)
    unsigned short* __restrict__ winw,        // wave's region in window slot 0 (uniform)
    unsigned short (*sHiP)[16][HSP],          // [2 parity][16][HSP]
    unsigned short (*sLoP)[16][HSP],
    const void* __restrict__ xp_all,
    unsigned short* __restrict__ out16, float* __restrict__ out32, int obf,
    const float* __restrict__ brec, const int* __restrict__ lens,
    float* __restrict__ hfin,
    int dir, int mg, int ub0, int l15, int quad, int lane) {
  constexpr int NB = NTC / 3;

  // per-lane ownership: rows quad*4+r, u-cols (ub0+lb)*16 + l15
  int ucl[NB]; bool cv[NB];
  float bz[NB], brg[NB], bh[NB];
#pragma unroll
  for (int lb = 0; lb < NB; ++lb) {
    int u = (ub0 + lb) * 16 + l15;
    bool v = (u < U_);
    cv[lb] = v;
    ucl[lb] = v ? u : 0;
    bz[lb] = brec[ucl[lb]]; brg[lb] = brec[U_ + ucl[lb]]; bh[lb] = brec[2 * U_ + ucl[lb]];
  }
  size_t xbase[4];
  int mylen[4];
#pragma unroll
  for (int r = 0; r < 4; ++r) {
    xbase[r] = ((size_t)dir * 65536 + (size_t)(mg * 16 + quad * 4 + r) * T_) * XPW;
    mylen[r] = lens[mg * 16 + quad * 4 + r];
  }
  float hold[NB][4];
#pragma unroll
  for (int lb = 0; lb < NB; ++lb)
#pragma unroll
    for (int r = 0; r < 4; ++r) hold[lb][r] = 0.f;

  const unsigned short* winL = winw + (size_t)lane * 8;

  // raw (unconverted) xp bits, double-buffered across steps
  unsigned int XA[NB][3][4], XB[NB][3][4];

  auto load_xp = [&](unsigned int (&X)[NB][3][4], int t) {
#pragma unroll
    for (int r = 0; r < 4; ++r) {
      size_t ro = xbase[r] + (size_t)t * XPW;
      if (XPF32) {
        const unsigned int* xr = (const unsigned int*)xp_all + ro;
#pragma unroll
        for (int lb = 0; lb < NB; ++lb) {
          X[lb][0][r] = xr[ucl[lb]];
          X[lb][1][r] = xr[U_ + ucl[lb]];
          X[lb][2][r] = xr[2 * U_ + ucl[lb]];
        }
      } else {
        const unsigned short* xr = (const unsigned short*)xp_all + ro;
#pragma unroll
        for (int lb = 0; lb < NB; ++lb) {
          X[lb][0][r] = (unsigned int)xr[ucl[lb]];
          X[lb][1][r] = (unsigned int)xr[U_ + ucl[lb]];
          X[lb][2][r] = (unsigned int)xr[2 * U_ + ucl[lb]];
        }
      }
    }
  };
  auto xval = [&](unsigned int x) -> float {
    if (XPF32) { union { unsigned int i; float f; } v; v.i = x; return v.f; }
    return b2f_bits((unsigned short)x);
  };
  auto dma_kb = [&](int kb) {
    const unsigned short* g = bpL + (size_t)kb * NTC * 512;
    unsigned short* l = winw + (size_t)(kb & 1) * SLOTSH;
#pragma unroll
    for (int nt = 0; nt < NTC; ++nt)
      dma16(g + (size_t)nt * 512, l + (size_t)nt * 512);
  };

  // prologue: prime both slots + step-0 xp, then drain + join h-zero barrier
  dma_kb(0);
  dma_kb(1);
  load_xp(XA, dir ? (T_ - 1) : 0);
  asm volatile("s_waitcnt vmcnt(0)" ::: "memory");
  __syncthreads();

  // one step: sweep kbs fwd (0..9) or bwd (9..0); slots hold the first two
  // kbs of this sweep already (left over from the previous opposite sweep).
  auto step = [&](auto fwd_c, int s, unsigned int (&Xu)[NB][3][4],
                  unsigned int (&Xp)[NB][3][4]) {
    constexpr bool FWD = decltype(fwd_c)::value;
    const int t = dir ? (T_ - 1 - s) : s;
    const int par = s & 1;
    const unsigned short (*hH)[HSP] = sHiP[par];
    const unsigned short (*hL)[HSP] = sLoP[par];

    floatx4 acc[NTC];
#pragma unroll
    for (int i = 0; i < NTC; ++i) acc[i] = {0.f, 0.f, 0.f, 0.f};

#pragma unroll
    for (int i = 0; i < 10; ++i) {
      const int kb = FWD ? i : 9 - i;
      // counted waits: i 0,1 resident; i 2..8 leave exactly the next batch
      // (NTC DMAs) in flight; i 9 drains the last batch.
      if (i >= 2 && i <= 8) wait_vm<NTC>();
      if (i == 9) wait_vm<0>();
      short8 ah = *(const short8*)&hH[l15][kb * 32 + quad * 8];
      short8 al = *(const short8*)&hL[l15][kb * 32 + quad * 8];
      short8 bfr[NTC];
#pragma unroll
      for (int nt = 0; nt < NTC; ++nt)
        bfr[nt] = *(const short8*)(winL + (size_t)(kb & 1) * SLOTSH + (size_t)nt * 512);
#pragma unroll
      for (int nt = 0; nt < NTC; ++nt)
        acc[nt] = __builtin_amdgcn_mfma_f32_16x16x32_bf16(ah, bfr[nt], acc[nt], 0, 0, 0);
#pragma unroll
      for (int nt = 0; nt < NTC; ++nt)
        acc[nt] = __builtin_amdgcn_mfma_f32_16x16x32_bf16(al, bfr[nt], acc[nt], 0, 0, 0);
      wait_lgkm0();                       // slot reads retired before overwrite
      if (i <= 7) dma_kb(FWD ? i + 2 : 7 - i);
    }

    // prefetch NEXT step's xp (after the vmcnt(0): it stays newest in queue,
    // ages a full epilogue+barrier+2 compute phases before any counted wait)
    {
      int tn = dir ? (t > 0 ? t - 1 : t) : (t < T_ - 1 ? t + 1 : t);
      load_xp(Xp, tn);
    }

    // epilogue: register-only inputs; writes go to par^1 buffer.
    unsigned short (*nH)[HSP] = sHiP[par ^ 1];
    unsigned short (*nL)[HSP] = sLoP[par ^ 1];
#pragma unroll
    for (int r = 0; r < 4; ++r) {
      const int row = quad * 4 + r;
      const bool m = (t < mylen[r]);
      const size_t ob = ((size_t)(mg * 16 + row) * T_ + t) * 600 + (size_t)dir * U_;
#pragma unroll
      for (int lb = 0; lb < NB; ++lb) {
        float z  = sigm_f(xval(Xu[lb][0][r]) + acc[lb * 3 + 0][r] + bz[lb]);
        float rg = sigm_f(xval(Xu[lb][1][r]) + acc[lb * 3 + 1][r] + brg[lb]);
        float hh = tanh_f(xval(Xu[lb][2][r]) + rg * (acc[lb * 3 + 2][r] + bh[lb]));
        float hn = z * hold[lb][r] + (1.f - z) * hh;
        float hw = m ? hn : hold[lb][r];
        hold[lb][r] = hw;
        if (cv[lb]) {
          float y = m ? hn : 0.f;
          if (obf) out16[ob + ucl[lb]] = f2b(y); else out32[ob + ucl[lb]] = y;
          unsigned short hib = f2b(hw);
          nH[row][ucl[lb]] = hib;
          nL[row][ucl[lb]] = f2b(hw - b2f_bits(hib));
        }
      }
    }
    // single per-step barrier: drain LDS writes only.
    wait_lgkm0();
    __builtin_amdgcn_s_barrier();
  };

#pragma unroll 1
  for (int s = 0; s < T_; s += 2) {
    step(BoolC<true>{}, s, XA, XB);
    step(BoolC<false>{}, s + 1, XB, XA);
  }

  // final state straight from registers
#pragma unroll
  for (int lb = 0; lb < NB; ++lb) {
    if (!cv[lb]) continue;
#pragma unroll
    for (int r = 0; r < 4; ++r)
      hfin[((size_t)dir * B_ + mg * 16 + quad * 4 + r) * 304 + ucl[lb]] = hold[lb][r];
  }
}

// ---------------- K4: GRU scan, 4 WGs x 16 batch rows per direction ----------------
template <bool XPF32>
__global__ __launch_bounds__(512, 2) void k_scan(const unsigned short* __restrict__ bpack,
                                                 const float* __restrict__ biasc,
                                                 const void* __restrict__ xp_all,
                                                 const int* __restrict__ lens,
                                                 const int* __restrict__ flags,
                                                 float* __restrict__ hfin,          // [2][64][304]
                                                 void* __restrict__ outraw) {
  __shared__ unsigned short sHi[2][16][HSP];               // parity double buffer
  __shared__ unsigned short sLo[2][16][HSP];
  __shared__ __align__(16) unsigned short win[2 * SLOTSH]; // DMA window, 2 slots

  const int tid = threadIdx.x;
  const int mg = blockIdx.x;        // m-group: batch rows 16mg..16mg+15
  const int dir = blockIdx.y;
  const int wave = tid >> 6, lane = tid & 63;
  const int l15 = lane & 15, quad = lane >> 4;
  const int obf = flags[0];
  unsigned short* out16 = (unsigned short*)outraw;
  float* out32 = (float*)outraw;

  const int UB0w = (wave < 3) ? wave * 3 : 9 + (wave - 3) * 2;
  const int FB   = (wave < 3) ? wave * 90 : 270 + (wave - 3) * 60;
  const int RBW  = (wave < 3) ? wave * 9 : 27 + (wave - 3) * 6;  // frag offset in slot

  // zero both h parity buffers (incl. the k-pad region 300..327)
  {
    unsigned int* p0 = (unsigned int*)&sHi[0][0][0];
    unsigned int* p1 = (unsigned int*)&sLo[0][0][0];
    for (int i = tid; i < 2 * 16 * HSP / 2; i += 512) { p0[i] = 0u; p1[i] = 0u; }
  }

  const unsigned short* bpL = bpack + ((size_t)dir * FRAGS_PER_DIR + FB) * 512 + (size_t)lane * 8;
  unsigned short* winw = &win[(size_t)RBW * 512];
  const float* brec = biasc + (size_t)dir * 2 * NU + NU;

  if (wave < 3)
    scan_loop<9, XPF32>(bpL, winw, sHi, sLo, xp_all, out16, out32, obf, brec, lens,
                        hfin, dir, mg, UB0w, l15, quad, lane);
  else
    scan_loop<6, XPF32>(bpL, winw, sHi, sLo, xp_all, out16, out32, obf, brec, lens,
                        hfin, dir, mg, UB0w, l15, quad, lane);
}

// ---------------- K5: state = relu(concat(h_f,h_b) @ w_fc + b_fc) ----------------
__global__ __launch_bounds__(320) void k_state(const float* __restrict__ hfin,
                                               const unsigned short* __restrict__ wfcc,
                                               const float* __restrict__ bfcc,
                                               const int* __restrict__ flags,
                                               void* __restrict__ outraw) {
  int b = blockIdx.x, u = threadIdx.x;
  if (u >= U_) return;
  int obf = flags[0];
  float acc = bfcc[u];
  const float* hf = hfin + (size_t)b * 304;
  const float* hb = hfin + ((size_t)B_ + b) * 304;
  for (int k = 0; k < U_; ++k) acc = fmaf(hf[k], b2f_bits(wfcc[(size_t)k * U_ + u]), acc);
  for (int k = 0; k < U_; ++k) acc = fmaf(hb[k], b2f_bits(wfcc[(size_t)(U_ + k) * U_ + u]), acc);
  float v = fmaxf(acc, 0.f);
  size_t oi = (size_t)B_ * T_ * 600 + (size_t)b * U_ + u;
  if (obf) ((unsigned short*)outraw)[oi] = f2b(v);
  else     ((float*)outraw)[oi] = v;
}

extern "C" void kernel_launch(void* const* d_in, const int* in_sizes, int n_in,
                              void* d_out, int out_size, void* d_ws, size_t ws_size,
                              hipStream_t stream) {
  const void* x    = d_in[0];
  const void* mask = d_in[1];
  const void* kf   = d_in[2];
  const void* rkf  = d_in[3];
  const void* bfw  = d_in[4];
  const void* kb   = d_in[5];
  const void* rkb  = d_in[6];
  const void* bbw  = d_in[7];
  const void* wfc  = d_in[8];
  const void* bfc  = d_in[9];

  char* ws = (char*)d_ws;
  size_t off = 0;
  auto alloc = [&](size_t bytes) { void* p = ws + off; off += (bytes + 255) & ~(size_t)255; return p; };
  int* flags            = (int*)alloc(256);
  int* lens             = (int*)alloc(256);
  unsigned short* xpad  = (unsigned short*)alloc((size_t)65536 * KP * 2);
  unsigned short* kpad  = (unsigned short*)alloc((size_t)2 * KP * NP * 2);
  unsigned short* rkc   = (unsigned short*)alloc((size_t)2 * D_ * NU * 2);
  unsigned short* bpack = (unsigned short*)alloc((size_t)2 * FRAGS_PER_DIR * 512 * 2);
  float* biasc          = (float*)alloc((size_t)2 * 2 * NU * 4);
  unsigned short* wfcc  = (unsigned short*)alloc((size_t)2 * U_ * U_ * 2);
  float* bfcc           = (float*)alloc((size_t)U_ * 4);
  float* hfin           = (float*)alloc((size_t)2 * B_ * 304 * 4);
  void* xp = (void*)(ws + off);
  size_t need_f32 = off + (size_t)2 * 65536 * XPW * 4;
  bool xpf32 = ws_size >= need_f32;

  k_detect<<<dim3(1), dim3(64), 0, stream>>>((const unsigned int*)x, (const unsigned char*)mask, flags);
  k_lengths<<<dim3(B_), dim3(256), 0, stream>>>((const unsigned char*)mask, flags, lens);
  k_xpad<<<dim3(65536 * 40 / 256), dim3(256), 0, stream>>>(x, flags, xpad);
  k_wpad<<<dim3((2 * KP * NP + 255) / 256), dim3(256), 0, stream>>>(kf, kb, flags, kpad);
  k_prep<<<dim3((2 * D_ * NU + 255) / 256), dim3(256), 0, stream>>>(rkf, rkb, bfw, bbw, wfc, bfc,
                                                                    flags, rkc, biasc, wfcc, bfcc);
  k_bpack<<<dim3((2 * FRAGS_PER_DIR * 512 + 255) / 256), dim3(256), 0, stream>>>(rkc, bpack);
  if (xpf32) {
    k_gemm<true><<<dim3(1024, 15, 2), dim3(256), 0, stream>>>(xpad, kpad, biasc, xp);
    k_scan<true><<<dim3(NWGM, 2), dim3(512), 0, stream>>>(bpack, biasc, xp, lens, flags, hfin, d_out);
  } else {
    k_gemm<false><<<dim3(1024, 15, 2), dim3(256), 0, stream>>>(xpad, kpad, biasc, xp);
    k_scan<false><<<dim3(NWGM, 2), dim3(512), 0, stream>>>(bpack, biasc, xp, lens, flags, hfin, d_out);
  }
  k_state<<<dim3(B_), dim3(320), 0, stream>>>(hfin, wfcc, bfcc, flags, d_out);
}